// Round 6
// baseline (736.568 us; speedup 1.0000x reference)
//
#include <hip/hip_runtime.h>
#include <hip/hip_bf16.h>

#define NSP   20000
#define NSPAT 10000
#define ESS   160000
#define EBIP  320000
#define ESP   320000

static inline int cdiv_host(long a, long b) { return (int)((a + b - 1) / b); }

__device__ __forceinline__ float wave_red_sum(float p) {
#pragma unroll
  for (int m = 32; m >= 1; m >>= 1) p += __shfl_xor(p, m, 64);
  return p;
}

__device__ __forceinline__ float bf2f(unsigned short u) {
  return __uint_as_float(((unsigned int)u) << 16);
}
__device__ __forceinline__ unsigned short f2bf(float f) {
  unsigned int u = __float_as_uint(f);
  unsigned int r = (u + 0x7FFF + ((u >> 16) & 1)) >> 16;  // RN-even
  return (unsigned short)r;
}

// ---------------------------------------------------------------------------
// species 96-wide prefix: [mean(32) | std(32) | vis(32)]; mask format
// detected per-block (0 = int32 {0,1}, 1 = bytes {0,1}, 2 = float {0,1.0f})
// ---------------------------------------------------------------------------
__global__ void build_spcat96(const float* __restrict__ mean, const float* __restrict__ stdv,
                              const void* __restrict__ mask,
                              float* __restrict__ out) {
  __shared__ int smode;
  if (threadIdx.x == 0) {
    const unsigned int* m = (const unsigned int*)mask;
    int allint = 1, allfloat = 1;
    for (int i = 0; i < 256; ++i) {
      unsigned int w = m[i];
      if (w != 0u && w != 1u) allint = 0;
      if (w != 0u && w != 0x3f800000u) allfloat = 0;
    }
    smode = allint ? 0 : (allfloat ? 2 : 1);
  }
  __syncthreads();
  int mode = smode;
  const long total = (long)NSP * 96;
  for (long i = (long)blockIdx.x * blockDim.x + threadIdx.x; i < total;
       i += (long)gridDim.x * blockDim.x) {
    int n = (int)(i / 96), c = (int)(i % 96);
    float v;
    if (c < 32) v = mean[(long)n * 32 + c];
    else if (c < 64) v = stdv[(long)n * 32 + (c - 32)];
    else {
      long j = (long)n * 32 + (c - 64);
      int mv;
      if (mode == 0) mv = ((const int*)mask)[j];
      else if (mode == 2) mv = (((const float*)mask)[j] != 0.0f);
      else mv = (int)((const unsigned char*)mask)[j];
      v = mv ? 0.f : 1.f;   // vis = ~mask
    }
    out[i] = v;
  }
}

__global__ void concat2_kernel(const float* __restrict__ A, int wa,
                               const float* __restrict__ B, int wb,
                               int M, float* __restrict__ out) {
  const int wt = wa + wb;
  const long total = (long)M * wt;
  for (long i = (long)blockIdx.x * blockDim.x + threadIdx.x; i < total;
       i += (long)gridDim.x * blockDim.x) {
    int m = (int)(i / wt), c = (int)(i % wt);
    out[i] = (c < wa) ? A[(long)m * wa + c] : B[(long)m * wb + (c - wa)];
  }
}

// ---------------------------------------------------------------------------
// CSR build, 8-way partitioned atomics.  Partition p = (combined_i >> 8) & 7.
// ---------------------------------------------------------------------------
__global__ void count3_kernel(
    const int* c1, int E1, int* cp1, int* rnk1, int n1,
    const int* c2, int E2, int* cp2, int* rnk2, int n2,
    const int* c3, int E3, int* cp3, int* rnk3, int n3) {
  int total = E1 + E2 + E3;
  for (int i = blockIdx.x * blockDim.x + threadIdx.x; i < total; i += gridDim.x * blockDim.x) {
    int p = (i >> 8) & 7;
    if (i < E1) {
      int d = c1[i]; rnk1[i] = atomicAdd(&cp1[p * n1 + d], 1);
    } else if (i < E1 + E2) {
      int j = i - E1;
      int d = c2[j]; rnk2[j] = atomicAdd(&cp2[p * n2 + d], 1);
    } else {
      int j = i - E1 - E2;
      int d = c3[j]; rnk3[j] = atomicAdd(&cp3[p * n3 + d], 1);
    }
  }
}

__global__ void merge3_kernel(int* cp1, int* c1, int n1,
                              int* cp2, int* c2, int n2,
                              int* cp3, int* c3, int n3) {
  int i = blockIdx.x * blockDim.x + threadIdx.x;
  int total = n1 + n2 + n3;
  if (i >= total) return;
  int *cp, *c; int n, d;
  if (i < n1) { cp = cp1; c = c1; n = n1; d = i; }
  else if (i < n1 + n2) { cp = cp2; c = c2; n = n2; d = i - n1; }
  else { cp = cp3; c = c3; n = n3; d = i - n1 - n2; }
  int s = 0;
#pragma unroll
  for (int p = 0; p < 8; ++p) { int t = cp[p * n + d]; cp[p * n + d] = s; s += t; }
  c[d] = s;
}

__global__ __launch_bounds__(1024) void scan3_kernel(
    const int* cntA, int nA, int* ptrA,
    const int* cntB, int nB, int* ptrB,
    const int* cntC, int nC, int* ptrC) {
  const int* cnt; int n; int* ptr;
  if (blockIdx.x == 0) { cnt = cntA; n = nA; ptr = ptrA; }
  else if (blockIdx.x == 1) { cnt = cntB; n = nB; ptr = ptrB; }
  else { cnt = cntC; n = nC; ptr = ptrC; }
  __shared__ int part[1024];
  int t = threadIdx.x;
  int ch = (n + 1023) / 1024;
  int beg = t * ch, end = min(beg + ch, n);
  int s = 0;
  for (int i = beg; i < end; ++i) s += cnt[i];
  part[t] = s;
  __syncthreads();
  for (int off = 1; off < 1024; off <<= 1) {
    int v = (t >= off) ? part[t - off] : 0;
    __syncthreads();
    part[t] += v;
    __syncthreads();
  }
  int run = (t == 0) ? 0 : part[t - 1];
  for (int i = beg; i < end; ++i) { ptr[i] = run; run += cnt[i]; }
  if (t == 1023) ptr[n] = part[1023];
}

__global__ void scatter3_kernel(
    const int* r1, const int* c1, const float* e1, int E1, const int* p1, const int* cp1, const int* k1, int n1, int* s1, float* a1,
    const int* r2, const int* c2, const float* e2, int E2, const int* p2, const int* cp2, const int* k2, int n2, int* s2, float* a2,
    const int* r3, const int* c3, const float* e3, int E3, const int* p3, const int* cp3, const int* k3, int n3, int* s3, float* a3) {
  int total = E1 + E2 + E3;
  for (int i = blockIdx.x * blockDim.x + threadIdx.x; i < total; i += gridDim.x * blockDim.x) {
    int p = (i >> 8) & 7;
    if (i < E1) {
      int d = c1[i];
      int pos = p1[d] + cp1[p * n1 + d] + k1[i];
      s1[pos] = r1[i]; a1[pos] = e1[i];
    } else if (i < E1 + E2) {
      int j = i - E1;
      int d = c2[j];
      int pos = p2[d] + cp2[p * n2 + d] + k2[j];
      s2[pos] = r2[j]; a2[pos] = e2[j];
    } else {
      int j = i - E1 - E2;
      int d = c3[j];
      int pos = p3[d] + cp3[p * n3 + d] + k3[j];
      s3[pos] = r3[j]; a3[pos] = e3[j];
    }
  }
}

// loop_ea = mean of incoming edge_attr, from contiguous CSR cea
__global__ void leafin_csr2(const int* ptrA, const float* ceaA, int nA, float* leaA,
                            const int* ptrB, const float* ceaB, int nB, float* leaB) {
  int i = blockIdx.x * blockDim.x + threadIdx.x;
  if (i >= nA + nB) return;
  const int* ptr; const float* cea; float* lea; int d;
  if (i < nA) { ptr = ptrA; cea = ceaA; lea = leaA; d = i; }
  else { ptr = ptrB; cea = ceaB; lea = leaB; d = i - nA; }
  int e0 = ptr[d], e1 = ptr[d + 1];
  float s = 0.f;
  for (int e = e0; e < e1; ++e) s += cea[e];
  lea[d] = s / (float)max(e1 - e0, 1);
}

// dot_e[h] = sum_c We[h*64+c] * a_e[h*64+c]; all 5 layers in one launch
__global__ void dote_all_kernel(const float* __restrict__ We0, const float* __restrict__ ae0,
                                const float* __restrict__ We1, const float* __restrict__ ae1,
                                const float* __restrict__ Web, const float* __restrict__ aeb,
                                const float* __restrict__ We2, const float* __restrict__ ae2,
                                const float* __restrict__ We3, const float* __restrict__ ae3,
                                float* __restrict__ dotes) {
  int b = blockIdx.x, t = threadIdx.x;
  const float *We, *ae;
  int n, off;
  switch (b) {
    case 0: We = We0; ae = ae0; n = 256; off = 0; break;
    case 1: We = We1; ae = ae1; n = 256; off = 4; break;
    case 2: We = Web; ae = aeb; n = 64;  off = 8; break;
    case 3: We = We2; ae = ae2; n = 256; off = 12; break;
    default: We = We3; ae = ae3; n = 256; off = 16; break;
  }
  if (t < n) {
    float p = wave_red_sum(We[t] * ae[t]);
    if ((t & 63) == 0) dotes[off + (t >> 6)] = p;
  }
}

struct XSrc { const float* p[5]; int w[5]; int n; };

// ---------------------------------------------------------------------------
// NOUT=64 projection, wave-per-row-group: W fully in LDS (one barrier), then
// each wave grid-strides over 4-row groups with NO barriers.  lane = col.
// X loads are wave-uniform float4 broadcasts.  mode: 0 = bias (skip store if
// Y null), 1 = bias+relu, 2 = final split (mean | softplus+eps)
// ---------------------------------------------------------------------------
template <int MAXK>
__global__ __launch_bounds__(256) void proj64w_kernel(
    XSrc xsrc, int M, int K,
    const float* __restrict__ W, const float* __restrict__ bias, int mode,
    const float* __restrict__ a_s, const float* __restrict__ a_d,
    float* __restrict__ al_s, float* __restrict__ al_d,
    float* __restrict__ Y, float* __restrict__ Y2) {
  __shared__ float wl[MAXK * 64];
  int t = threadIdx.x;
  {
    const float4* ws = (const float4*)W;
    float4* wd = (float4*)wl;
    for (int i = t; i < (K * 64) >> 2; i += 256) wd[i] = ws[i];
  }
  __syncthreads();
  int lane = t & 63;
  int gw = blockIdx.x * 4 + (t >> 6);
  int nw = gridDim.x * 4;
  float bv = bias ? bias[lane] : 0.f;
  float asv = a_s ? a_s[lane] : 0.f;
  float adv = a_d ? a_d[lane] : 0.f;

  for (long r0 = (long)gw * 4; r0 < M; r0 += (long)nw * 4) {
    float acc0 = 0.f, acc1 = 0.f, acc2 = 0.f, acc3 = 0.f;
    long r1c = min(r0 + 1, (long)M - 1);
    long r2c = min(r0 + 2, (long)M - 1);
    long r3c = min(r0 + 3, (long)M - 1);
    int kbase = 0;
    for (int s = 0; s < xsrc.n; ++s) {
      const float* Xp = xsrc.p[s];
      int w = xsrc.w[s];
      const float* x0 = Xp + r0 * w;
      const float* x1 = Xp + r1c * w;
      const float* x2 = Xp + r2c * w;
      const float* x3 = Xp + r3c * w;
      for (int k = 0; k < w; k += 4) {
        float4 a = *(const float4*)(x0 + k);
        float4 b = *(const float4*)(x1 + k);
        float4 c = *(const float4*)(x2 + k);
        float4 d = *(const float4*)(x3 + k);
        const float* wp = wl + (kbase + k) * 64 + lane;
        float w0 = wp[0], w1 = wp[64], w2 = wp[128], w3 = wp[192];
        acc0 = fmaf(a.x, w0, acc0); acc1 = fmaf(b.x, w0, acc1);
        acc2 = fmaf(c.x, w0, acc2); acc3 = fmaf(d.x, w0, acc3);
        acc0 = fmaf(a.y, w1, acc0); acc1 = fmaf(b.y, w1, acc1);
        acc2 = fmaf(c.y, w1, acc2); acc3 = fmaf(d.y, w1, acc3);
        acc0 = fmaf(a.z, w2, acc0); acc1 = fmaf(b.z, w2, acc1);
        acc2 = fmaf(c.z, w2, acc2); acc3 = fmaf(d.z, w2, acc3);
        acc0 = fmaf(a.w, w3, acc0); acc1 = fmaf(b.w, w3, acc1);
        acc2 = fmaf(c.w, w3, acc2); acc3 = fmaf(d.w, w3, acc3);
      }
      kbase += w;
    }
    float accs[4] = {acc0, acc1, acc2, acc3};
    for (int j = 0; j < 4; ++j) {
      long m = r0 + j;
      if (m >= M) break;
      float v = accs[j] + bv;
      if (mode == 1) {
        Y[m * 64 + lane] = fmaxf(v, 0.f);
      } else if (mode == 2) {
        if (lane < 32) Y[m * 32 + lane] = v;
        else Y2[m * 32 + (lane - 32)] =
            fmaxf(v, 0.f) + log1pf(__expf(-fabsf(v))) + 1e-6f;
      } else if (Y) {
        Y[m * 64 + lane] = v;
      }
      if (a_s) {
        float s = wave_red_sum(accs[j] * asv);
        if (lane == 0) al_s[m] = s;
      }
      if (a_d) {
        float s = wave_red_sum(accs[j] * adv);
        if (lane == 0) al_d[m] = s;
      }
    }
  }
}

// ---------------------------------------------------------------------------
// NOUT=256 projection (tiled, BR=32): X and W staged in LDS.
// mode: 3 = store bf16 (used for all H=4 hs tables)
// ---------------------------------------------------------------------------
__global__ __launch_bounds__(256) void proj_kernel(
    XSrc xsrc, int M, int K,
    const float* __restrict__ W, const float* __restrict__ bias, int mode,
    const float* __restrict__ a_s, const float* __restrict__ a_d,
    float* __restrict__ al_s, float* __restrict__ al_d,
    float* __restrict__ Y, float* __restrict__ Y2) {
  constexpr int NOUT = 256;
  constexpr int KC = 32;
  constexpr int RPT = 8;
  constexpr int BR = 32;
  constexpr int KCP = 36;
  constexpr int H = 4;
  __shared__ float wl[KC * NOUT];
  __shared__ float xl[BR * KCP];

  int t = threadIdx.x;
  int cg = t & 63, rg = t >> 6;
  int c0 = cg * 4;
  long row0 = (long)blockIdx.x * BR;

  float acc[RPT][4];
#pragma unroll
  for (int r = 0; r < RPT; ++r)
#pragma unroll
    for (int j = 0; j < 4; ++j) acc[r][j] = 0.f;

  for (int k0 = 0; k0 < K; k0 += KC) {
    int kc = min(KC, K - k0);
    int seg = 0; int base = 0;
    while (k0 >= base + xsrc.w[seg]) { base += xsrc.w[seg]; ++seg; }
    const float* Xp = xsrc.p[seg];
    int stride = xsrc.w[seg];
    int kloc = k0 - base;

    __syncthreads();
    {
      const float4* wsrc = (const float4*)(W + (long)k0 * NOUT);
      float4* wdst = (float4*)wl;
      for (int i = t; i < (kc * NOUT) >> 2; i += 256) wdst[i] = wsrc[i];
    }
    for (int i = t; i < BR * 8; i += 256) {
      int r = i >> 3, kq = (i & 7) * 4;
      if (kq < kc) {
        long rr = row0 + r; if (rr >= M) rr = M - 1;
        float4 v = *(const float4*)(Xp + rr * stride + kloc + kq);
        *(float4*)(xl + r * KCP + kq) = v;
      }
    }
    __syncthreads();

    for (int kg = 0; kg < kc; kg += 4) {
      float4 w0 = *(const float4*)(wl + (kg + 0) * NOUT + c0);
      float4 w1 = *(const float4*)(wl + (kg + 1) * NOUT + c0);
      float4 w2 = *(const float4*)(wl + (kg + 2) * NOUT + c0);
      float4 w3 = *(const float4*)(wl + (kg + 3) * NOUT + c0);
      float4 xv[RPT];
#pragma unroll
      for (int r = 0; r < RPT; ++r)
        xv[r] = *(const float4*)(xl + (rg * RPT + r) * KCP + kg);
#pragma unroll
      for (int r = 0; r < RPT; ++r) {
        acc[r][0] = fmaf(xv[r].x, w0.x, acc[r][0]);
        acc[r][1] = fmaf(xv[r].x, w0.y, acc[r][1]);
        acc[r][2] = fmaf(xv[r].x, w0.z, acc[r][2]);
        acc[r][3] = fmaf(xv[r].x, w0.w, acc[r][3]);
        acc[r][0] = fmaf(xv[r].y, w1.x, acc[r][0]);
        acc[r][1] = fmaf(xv[r].y, w1.y, acc[r][1]);
        acc[r][2] = fmaf(xv[r].y, w1.z, acc[r][2]);
        acc[r][3] = fmaf(xv[r].y, w1.w, acc[r][3]);
        acc[r][0] = fmaf(xv[r].z, w2.x, acc[r][0]);
        acc[r][1] = fmaf(xv[r].z, w2.y, acc[r][1]);
        acc[r][2] = fmaf(xv[r].z, w2.z, acc[r][2]);
        acc[r][3] = fmaf(xv[r].z, w2.w, acc[r][3]);
        acc[r][0] = fmaf(xv[r].w, w3.x, acc[r][0]);
        acc[r][1] = fmaf(xv[r].w, w3.y, acc[r][1]);
        acc[r][2] = fmaf(xv[r].w, w3.z, acc[r][2]);
        acc[r][3] = fmaf(xv[r].w, w3.w, acc[r][3]);
      }
    }
  }

  float4 asv = make_float4(0.f, 0.f, 0.f, 0.f);
  float4 adv = make_float4(0.f, 0.f, 0.f, 0.f);
  if (a_s) asv = *(const float4*)(a_s + c0);
  if (a_d) adv = *(const float4*)(a_d + c0);

#pragma unroll
  for (int r = 0; r < RPT; ++r) {
    long m = row0 + (long)rg * RPT + r;
    bool ok = m < M;
    if (ok && mode == 3) {
      ushort4 o;
      o.x = f2bf(acc[r][0]); o.y = f2bf(acc[r][1]);
      o.z = f2bf(acc[r][2]); o.w = f2bf(acc[r][3]);
      *(ushort4*)((unsigned short*)Y + m * NOUT + c0) = o;
    }
    if (a_s) {
      float s = acc[r][0] * asv.x + acc[r][1] * asv.y + acc[r][2] * asv.z + acc[r][3] * asv.w;
      s += __shfl_xor(s, 1); s += __shfl_xor(s, 2);
      s += __shfl_xor(s, 4); s += __shfl_xor(s, 8);
      if (ok && (cg & 15) == 0) al_s[m * H + (c0 >> 6)] = s;
    }
    if (a_d) {
      float s = acc[r][0] * adv.x + acc[r][1] * adv.y + acc[r][2] * adv.z + acc[r][3] * adv.w;
      s += __shfl_xor(s, 1); s += __shfl_xor(s, 2);
      s += __shfl_xor(s, 4); s += __shfl_xor(s, 8);
      if (ok && (cg & 15) == 0) al_d[m * H + (c0 >> 6)] = s;
    }
  }
  (void)bias; (void)Y2;
}

// ---------------------------------------------------------------------------
// GAT pass A: attention weights.  thread = (node, head), h fastest.
// ---------------------------------------------------------------------------
template <int H, bool SELFLOOP>
__global__ void attn_kernel(
    int Nd, const int* __restrict__ dptr, const int* __restrict__ csr_src,
    const float* __restrict__ csr_ea, const float* __restrict__ al_s,
    const float* __restrict__ al_d, const float* __restrict__ dote,
    const float* __restrict__ loop_ea,
    float* __restrict__ alpha, float* __restrict__ aloop, float* __restrict__ invden) {
  int tid = blockIdx.x * blockDim.x + threadIdx.x;
  if (tid >= Nd * H) return;
  int n = tid / H, h = tid % H;
  float ald = al_d[(long)n * H + h];
  float de = dote[h];
  int e0 = dptr[n], e1 = dptr[n + 1];
  float m = -INFINITY;
  for (int e = e0; e < e1; ++e) {
    int src = csr_src[e];
    float l = al_s[(long)src * H + h] + ald + csr_ea[e] * de;
    l = (l > 0.f) ? l : 0.2f * l;
    m = fmaxf(m, l);
  }
  float lloop = 0.f;
  if (SELFLOOP) {
    lloop = al_s[(long)n * H + h] + ald + loop_ea[n] * de;
    lloop = (lloop > 0.f) ? lloop : 0.2f * lloop;
    m = fmaxf(m, lloop);
  }
  float den = 0.f;
  for (int e = e0; e < e1; ++e) {
    int src = csr_src[e];
    float l = al_s[(long)src * H + h] + ald + csr_ea[e] * de;
    l = (l > 0.f) ? l : 0.2f * l;
    float ex = __expf(l - m);
    den += ex;
    alpha[(long)e * H + h] = ex;
  }
  if (SELFLOOP) {
    float ex = __expf(lloop - m);
    den += ex;
    aloop[(long)n * H + h] = ex;
  }
  invden[(long)n * H + h] = 1.f / (den + 1e-16f);
}

// ---------------------------------------------------------------------------
// GAT pass B, H=4 C=64 over bf16 hs (512B rows): one wave per node.
// ---------------------------------------------------------------------------
__device__ __forceinline__ void fma4_bf(float4& a, float al, ushort4 u) {
  a.x = fmaf(al, bf2f(u.x), a.x); a.y = fmaf(al, bf2f(u.y), a.y);
  a.z = fmaf(al, bf2f(u.z), a.z); a.w = fmaf(al, bf2f(u.w), a.w);
}

template <bool SELFLOOP>
__global__ __launch_bounds__(256) void agg4_kernel(
    int Nd, const int* __restrict__ dptr, const int* __restrict__ csr_src,
    const float* __restrict__ alpha, const float* __restrict__ aloop,
    const float* __restrict__ invden, const unsigned short* __restrict__ hs,
    const float* __restrict__ bias, float* __restrict__ out) {
  int wave = threadIdx.x >> 6, lane = threadIdx.x & 63;
  int n = blockIdx.x * 4 + wave;
  if (n >= Nd) return;
  int h = lane >> 4;
  int e0 = dptr[n], e1 = dptr[n + 1];
  float4 a0v = make_float4(0.f, 0.f, 0.f, 0.f);
  float4 a1v = make_float4(0.f, 0.f, 0.f, 0.f);
  int e = e0;
  for (; e + 2 <= e1; e += 2) {
    int s0 = csr_src[e], s1 = csr_src[e + 1];
    float a0 = alpha[(long)e * 4 + h];
    float a1 = alpha[(long)(e + 1) * 4 + h];
    ushort4 u0 = *(const ushort4*)(hs + (long)s0 * 256 + lane * 4);
    ushort4 u1 = *(const ushort4*)(hs + (long)s1 * 256 + lane * 4);
    fma4_bf(a0v, a0, u0);
    fma4_bf(a1v, a1, u1);
  }
  if (e < e1) {
    int s0 = csr_src[e];
    float a0 = alpha[(long)e * 4 + h];
    ushort4 u0 = *(const ushort4*)(hs + (long)s0 * 256 + lane * 4);
    fma4_bf(a0v, a0, u0);
  }
  a0v.x += a1v.x; a0v.y += a1v.y; a0v.z += a1v.z; a0v.w += a1v.w;
  if (SELFLOOP) {
    float a = aloop[(long)n * 4 + h];
    ushort4 u = *(const ushort4*)(hs + (long)n * 256 + lane * 4);
    fma4_bf(a0v, a, u);
  }
  float inv = invden[(long)n * 4 + h];
  a0v.x *= inv; a0v.y *= inv; a0v.z *= inv; a0v.w *= inv;
  a0v.x += __shfl_xor(a0v.x, 16); a0v.y += __shfl_xor(a0v.y, 16);
  a0v.z += __shfl_xor(a0v.z, 16); a0v.w += __shfl_xor(a0v.w, 16);
  a0v.x += __shfl_xor(a0v.x, 32); a0v.y += __shfl_xor(a0v.y, 32);
  a0v.z += __shfl_xor(a0v.z, 32); a0v.w += __shfl_xor(a0v.w, 32);
  if (lane < 16) {
    float4 b = *(const float4*)(bias + lane * 4);
    float4 o;
    o.x = fmaxf(a0v.x * 0.25f + b.x, 0.f);
    o.y = fmaxf(a0v.y * 0.25f + b.y, 0.f);
    o.z = fmaxf(a0v.z * 0.25f + b.z, 0.f);
    o.w = fmaxf(a0v.w * 0.25f + b.w, 0.f);
    *(float4*)(out + (long)n * 64 + lane * 4) = o;
  }
}

// GAT pass B, H=1 C=64 (fp32 hs): wave per node, lane = channel.
__global__ __launch_bounds__(256) void agg1_kernel(
    int Nd, const int* __restrict__ dptr, const int* __restrict__ csr_src,
    const float* __restrict__ alpha, const float* __restrict__ invden,
    const float* __restrict__ hs, const float* __restrict__ bias,
    float* __restrict__ out) {
  int wave = threadIdx.x >> 6, lane = threadIdx.x & 63;
  int n = blockIdx.x * 4 + wave;
  if (n >= Nd) return;
  int e0 = dptr[n], e1 = dptr[n + 1];
  float acc0 = 0.f, acc1 = 0.f;
  int e = e0;
  for (; e + 2 <= e1; e += 2) {
    int s0 = csr_src[e], s1 = csr_src[e + 1];
    acc0 = fmaf(alpha[e], hs[(long)s0 * 64 + lane], acc0);
    acc1 = fmaf(alpha[e + 1], hs[(long)s1 * 64 + lane], acc1);
  }
  if (e < e1) acc0 = fmaf(alpha[e], hs[(long)csr_src[e] * 64 + lane], acc0);
  acc0 += acc1;
  float o = acc0 * invden[n];
  out[(long)n * 64 + lane] = fmaxf(o + bias[lane], 0.f);
}

// ---------------------------------------------------------------------------
extern "C" void kernel_launch(void* const* d_in, const int* in_sizes, int n_in,
                              void* d_out, int out_size, void* d_ws, size_t ws_size,
                              hipStream_t stream) {
  const float* sp_mean = (const float*)d_in[0];
  const float* sp_std  = (const float*)d_in[1];
  const void*  nanmask = d_in[2];
  const float* sp_gen  = (const float*)d_in[3];
  const float* sp_phy  = (const float*)d_in[4];
  const float* spat_x  = (const float*)d_in[5];
  const float* spat_g  = (const float*)d_in[6];
  const int*   ss_ei   = (const int*)d_in[7];
  const float* ss_ea   = (const float*)d_in[8];
  const int*   bip_ei  = (const int*)d_in[9];
  const float* bip_ea  = (const float*)d_in[10];
  const int*   sp_ei   = (const int*)d_in[11];
  const float* sp_ea   = (const float*)d_in[12];
  const float* sg0_W = (const float*)d_in[13]; const float* sg0_as = (const float*)d_in[14];
  const float* sg0_ad = (const float*)d_in[15]; const float* sg0_ae = (const float*)d_in[16];
  const float* sg0_We = (const float*)d_in[17]; const float* sg0_b = (const float*)d_in[18];
  const float* sg1_W = (const float*)d_in[19]; const float* sg1_as = (const float*)d_in[20];
  const float* sg1_ad = (const float*)d_in[21]; const float* sg1_ae = (const float*)d_in[22];
  const float* sg1_We = (const float*)d_in[23]; const float* sg1_b = (const float*)d_in[24];
  const float* pg0_W = (const float*)d_in[25]; const float* pg0_as = (const float*)d_in[26];
  const float* pg0_ad = (const float*)d_in[27]; const float* pg0_ae = (const float*)d_in[28];
  const float* pg0_We = (const float*)d_in[29]; const float* pg0_b = (const float*)d_in[30];
  const float* pg1_W = (const float*)d_in[31]; const float* pg1_as = (const float*)d_in[32];
  const float* pg1_ad = (const float*)d_in[33]; const float* pg1_ae = (const float*)d_in[34];
  const float* pg1_We = (const float*)d_in[35]; const float* pg1_b = (const float*)d_in[36];
  const float* bp_Ws = (const float*)d_in[37]; const float* bp_Wd = (const float*)d_in[38];
  const float* bp_as = (const float*)d_in[39]; const float* bp_ad = (const float*)d_in[40];
  const float* bp_ae = (const float*)d_in[41]; const float* bp_We = (const float*)d_in[42];
  const float* bp_b  = (const float*)d_in[43];
  const float* sl_W  = (const float*)d_in[44]; const float* sl_b  = (const float*)d_in[45];
  const float* fc_W  = (const float*)d_in[46]; const float* fc_b  = (const float*)d_in[47];

  // ---- workspace layout ----
  char* wsb = (char*)d_ws;
  size_t off = 0;
  auto A = [&](size_t nbytes) -> void* {
    void* p = wsb + off;
    off += (nbytes + 255) & ~(size_t)255;
    return p;
  };
  // --- zeroed region (single memset): partitioned counters ---
  int* ss_cp = (int*)A((size_t)8 * NSPAT * 4);
  int* bp_cp = (int*)A((size_t)8 * NSP * 4);
  int* pp_cp = (int*)A((size_t)8 * NSP * 4);
  size_t zbytes = off;
  // --- rest ---
  int*   ss_cnt = (int*)A((NSPAT + 1) * 4);
  int*   bp_cnt = (int*)A((NSP + 1) * 4);
  int*   pp_cnt = (int*)A((NSP + 1) * 4);
  float* dotes = (float*)A(5 * 4 * sizeof(float));
  float* alS   = (float*)A((size_t)NSP * 4 * 4);
  float* alD   = (float*)A((size_t)NSP * 4 * 4);
  float* spc96 = (float*)A((size_t)NSP * 96 * 4);
  float* sp_in = (float*)A((size_t)NSP * 64 * 4);
  float* h0    = (float*)A((size_t)NSPAT * 16 * 4);
  float* h_a   = (float*)A((size_t)NSPAT * 64 * 4);
  float* h_b   = (float*)A((size_t)NSPAT * 64 * 4);
  float* HS    = (float*)A((size_t)NSP * 256 * 4);   // bf16 hs rows
  float* sts   = (float*)A((size_t)NSP * 64 * 4);
  float* x1    = (float*)A((size_t)NSP * 64 * 4);
  int*   ss_ptr = (int*)A((NSPAT + 1) * 4);
  int*   ss_src = (int*)A((size_t)ESS * 4);
  float* ss_cea = (float*)A((size_t)ESS * 4);
  int*   ss_rnk = (int*)A((size_t)ESS * 4);
  float* ss_lea = (float*)A((size_t)NSPAT * 4);
  int*   bp_ptr = (int*)A((NSP + 1) * 4);
  int*   bp_src = (int*)A((size_t)EBIP * 4);
  float* bp_cea = (float*)A((size_t)EBIP * 4);
  int*   bp_rnk = (int*)A((size_t)EBIP * 4);
  int*   pp_ptr = (int*)A((NSP + 1) * 4);
  int*   pp_src = (int*)A((size_t)ESP * 4);
  float* pp_cea = (float*)A((size_t)ESP * 4);
  int*   pp_rnk = (int*)A((size_t)ESP * 4);
  float* pp_lea = (float*)A((size_t)NSP * 4);
  float* ss_alpha = (float*)A((size_t)ESS * 4 * 4);
  float* ss_aloop = (float*)A((size_t)NSPAT * 4 * 4);
  float* ss_invd  = (float*)A((size_t)NSPAT * 4 * 4);
  float* bp_alpha = (float*)A((size_t)EBIP * 4);
  float* bp_invd  = (float*)A((size_t)NSP * 4);
  float* pp_alpha = (float*)A((size_t)ESP * 4 * 4);
  float* pp_aloop = (float*)A((size_t)NSP * 4 * 4);
  float* pp_invd  = (float*)A((size_t)NSP * 4 * 4);
  (void)ws_size; (void)in_sizes; (void)n_in; (void)out_size;

  const int TB = 256;
  hipMemsetAsync(wsb, 0, zbytes, stream);

  // ---- graph builds: partitioned count -> merge -> scan -> scatter ----
  count3_kernel<<<cdiv_host(ESS + EBIP + ESP, TB), TB, 0, stream>>>(
      ss_ei + ESS, ESS, ss_cp, ss_rnk, NSPAT,
      bip_ei + EBIP, EBIP, bp_cp, bp_rnk, NSP,
      sp_ei + ESP, ESP, pp_cp, pp_rnk, NSP);
  merge3_kernel<<<cdiv_host(NSPAT + NSP + NSP, TB), TB, 0, stream>>>(
      ss_cp, ss_cnt, NSPAT, bp_cp, bp_cnt, NSP, pp_cp, pp_cnt, NSP);
  scan3_kernel<<<3, 1024, 0, stream>>>(ss_cnt, NSPAT, ss_ptr, bp_cnt, NSP, bp_ptr, pp_cnt, NSP, pp_ptr);
  scatter3_kernel<<<cdiv_host(ESS + EBIP + ESP, TB), TB, 0, stream>>>(
      ss_ei, ss_ei + ESS, ss_ea, ESS, ss_ptr, ss_cp, ss_rnk, NSPAT, ss_src, ss_cea,
      bip_ei, bip_ei + EBIP, bip_ea, EBIP, bp_ptr, bp_cp, bp_rnk, NSP, bp_src, bp_cea,
      sp_ei, sp_ei + ESP, sp_ea, ESP, pp_ptr, pp_cp, pp_rnk, NSP, pp_src, pp_cea);
  leafin_csr2<<<cdiv_host(NSPAT + NSP, TB), TB, 0, stream>>>(
      ss_ptr, ss_cea, NSPAT, ss_lea, pp_ptr, pp_cea, NSP, pp_lea);

  dote_all_kernel<<<5, 256, 0, stream>>>(sg0_We, sg0_ae, sg1_We, sg1_ae, bp_We, bp_ae,
                                         pg0_We, pg0_ae, pg1_We, pg1_ae, dotes);

  // ---- species input MLP ----
  build_spcat96<<<cdiv_host((long)NSP * 96, TB), TB, 0, stream>>>(sp_mean, sp_std, nanmask, spc96);
  {
    XSrc xs{}; xs.p[0] = spc96; xs.w[0] = 96; xs.p[1] = sp_gen; xs.w[1] = 64;
    xs.p[2] = sp_phy; xs.w[2] = 128; xs.n = 3;
    proj64w_kernel<288><<<256, TB, 0, stream>>>(xs, NSP, 288, sl_W, sl_b, 1,
        nullptr, nullptr, nullptr, nullptr, sp_in, nullptr);
  }

  // ---- spatial GNN ----
  concat2_kernel<<<cdiv_host((long)NSPAT * 16, TB), TB, 0, stream>>>(spat_x, 12, spat_g, 4, NSPAT, h0);
  {
    XSrc xs{}; xs.p[0] = h0; xs.w[0] = 16; xs.n = 1;
    proj_kernel<<<cdiv_host(NSPAT, 32), TB, 0, stream>>>(xs, NSPAT, 16, sg0_W, nullptr, 3,
        sg0_as, sg0_ad, alS, alD, HS, nullptr);
  }
  attn_kernel<4, true><<<cdiv_host((long)NSPAT * 4, TB), TB, 0, stream>>>(
      NSPAT, ss_ptr, ss_src, ss_cea, alS, alD, dotes + 0, ss_lea, ss_alpha, ss_aloop, ss_invd);
  agg4_kernel<true><<<cdiv_host(NSPAT, 4), TB, 0, stream>>>(
      NSPAT, ss_ptr, ss_src, ss_alpha, ss_aloop, ss_invd, (const unsigned short*)HS, sg0_b, h_a);
  {
    XSrc xs{}; xs.p[0] = h_a; xs.w[0] = 64; xs.n = 1;
    proj_kernel<<<cdiv_host(NSPAT, 32), TB, 0, stream>>>(xs, NSPAT, 64, sg1_W, nullptr, 3,
        sg1_as, sg1_ad, alS, alD, HS, nullptr);
  }
  attn_kernel<4, true><<<cdiv_host((long)NSPAT * 4, TB), TB, 0, stream>>>(
      NSPAT, ss_ptr, ss_src, ss_cea, alS, alD, dotes + 4, ss_lea, ss_alpha, ss_aloop, ss_invd);
  agg4_kernel<true><<<cdiv_host(NSPAT, 4), TB, 0, stream>>>(
      NSPAT, ss_ptr, ss_src, ss_alpha, ss_aloop, ss_invd, (const unsigned short*)HS, sg1_b, h_b);

  // ---- bipartite GAT (spatial -> species), H=1, concat ----
  {
    XSrc xs{}; xs.p[0] = h_b; xs.w[0] = 64; xs.n = 1;
    proj64w_kernel<64><<<256, TB, 0, stream>>>(xs, NSPAT, 64, bp_Ws, nullptr, 0,
        bp_as, nullptr, alS, nullptr, h_a, nullptr);   // h_a := hs_src (fp32)
  }
  {
    XSrc xs{}; xs.p[0] = sp_gen; xs.w[0] = 64; xs.p[1] = sp_phy; xs.w[1] = 128; xs.n = 2;
    proj64w_kernel<192><<<256, TB, 0, stream>>>(xs, NSP, 192, bp_Wd, nullptr, 0,
        nullptr, bp_ad, nullptr, alD, nullptr, nullptr);   // only al_d needed
  }
  attn_kernel<1, false><<<cdiv_host(NSP, TB), TB, 0, stream>>>(
      NSP, bp_ptr, bp_src, bp_cea, alS, alD, dotes + 8, nullptr, bp_alpha, nullptr, bp_invd);
  agg1_kernel<<<cdiv_host(NSP, 4), TB, 0, stream>>>(
      NSP, bp_ptr, bp_src, bp_alpha, bp_invd, h_a, bp_b, sts);

  // ---- species GNN ----
  {
    XSrc xs{}; xs.p[0] = sts; xs.w[0] = 64; xs.p[1] = sp_in; xs.w[1] = 64; xs.n = 2;
    proj_kernel<<<cdiv_host(NSP, 32), TB, 0, stream>>>(xs, NSP, 128, pg0_W, nullptr, 3,
        pg0_as, pg0_ad, alS, alD, HS, nullptr);
  }
  attn_kernel<4, true><<<cdiv_host((long)NSP * 4, TB), TB, 0, stream>>>(
      NSP, pp_ptr, pp_src, pp_cea, alS, alD, dotes + 12, pp_lea, pp_alpha, pp_aloop, pp_invd);
  agg4_kernel<true><<<cdiv_host(NSP, 4), TB, 0, stream>>>(
      NSP, pp_ptr, pp_src, pp_alpha, pp_aloop, pp_invd, (const unsigned short*)HS, pg0_b, x1);
  {
    XSrc xs{}; xs.p[0] = x1; xs.w[0] = 64; xs.n = 1;
    proj_kernel<<<cdiv_host(NSP, 32), TB, 0, stream>>>(xs, NSP, 64, pg1_W, nullptr, 3,
        pg1_as, pg1_ad, alS, alD, HS, nullptr);
  }
  attn_kernel<4, true><<<cdiv_host((long)NSP * 4, TB), TB, 0, stream>>>(
      NSP, pp_ptr, pp_src, pp_cea, alS, alD, dotes + 16, pp_lea, pp_alpha, pp_aloop, pp_invd);
  agg4_kernel<true><<<cdiv_host(NSP, 4), TB, 0, stream>>>(
      NSP, pp_ptr, pp_src, pp_alpha, pp_aloop, pp_invd, (const unsigned short*)HS, pg1_b, sts);

  // ---- final linear fused with split/softplus ----
  {
    XSrc xs{}; xs.p[0] = sts; xs.w[0] = 64; xs.n = 1;
    proj64w_kernel<64><<<256, TB, 0, stream>>>(xs, NSP, 64, fc_W, fc_b, 2,
        nullptr, nullptr, nullptr, nullptr, (float*)d_out, (float*)d_out + (long)NSP * 32);
  }
}

// Round 7
// 694.086 us; speedup vs baseline: 1.0612x; 1.0612x over previous
//
#include <hip/hip_runtime.h>
#include <hip/hip_bf16.h>

#define NSP   20000
#define NSPAT 10000
#define ESS   160000
#define EBIP  320000
#define ESP   320000

static inline int cdiv_host(long a, long b) { return (int)((a + b - 1) / b); }

__device__ __forceinline__ float wave_red_sum(float p) {
#pragma unroll
  for (int m = 32; m >= 1; m >>= 1) p += __shfl_xor(p, m, 64);
  return p;
}

__device__ __forceinline__ float bf2f(unsigned short u) {
  return __uint_as_float(((unsigned int)u) << 16);
}
__device__ __forceinline__ unsigned short f2bf(float f) {
  unsigned int u = __float_as_uint(f);
  unsigned int r = (u + 0x7FFF + ((u >> 16) & 1)) >> 16;  // RN-even
  return (unsigned short)r;
}

// ---------------------------------------------------------------------------
// species 96-wide prefix: [mean(32) | std(32) | vis(32)]; mask format
// detected per-block (0 = int32 {0,1}, 1 = bytes {0,1}, 2 = float {0,1.0f})
// ---------------------------------------------------------------------------
__global__ void build_spcat96(const float* __restrict__ mean, const float* __restrict__ stdv,
                              const void* __restrict__ mask,
                              float* __restrict__ out) {
  __shared__ int smode;
  if (threadIdx.x == 0) {
    const unsigned int* m = (const unsigned int*)mask;
    int allint = 1, allfloat = 1;
    for (int i = 0; i < 256; ++i) {
      unsigned int w = m[i];
      if (w != 0u && w != 1u) allint = 0;
      if (w != 0u && w != 0x3f800000u) allfloat = 0;
    }
    smode = allint ? 0 : (allfloat ? 2 : 1);
  }
  __syncthreads();
  int mode = smode;
  const long total = (long)NSP * 96;
  for (long i = (long)blockIdx.x * blockDim.x + threadIdx.x; i < total;
       i += (long)gridDim.x * blockDim.x) {
    int n = (int)(i / 96), c = (int)(i % 96);
    float v;
    if (c < 32) v = mean[(long)n * 32 + c];
    else if (c < 64) v = stdv[(long)n * 32 + (c - 32)];
    else {
      long j = (long)n * 32 + (c - 64);
      int mv;
      if (mode == 0) mv = ((const int*)mask)[j];
      else if (mode == 2) mv = (((const float*)mask)[j] != 0.0f);
      else mv = (int)((const unsigned char*)mask)[j];
      v = mv ? 0.f : 1.f;   // vis = ~mask
    }
    out[i] = v;
  }
}

__global__ void concat2_kernel(const float* __restrict__ A, int wa,
                               const float* __restrict__ B, int wb,
                               int M, float* __restrict__ out) {
  const int wt = wa + wb;
  const long total = (long)M * wt;
  for (long i = (long)blockIdx.x * blockDim.x + threadIdx.x; i < total;
       i += (long)gridDim.x * blockDim.x) {
    int m = (int)(i / wt), c = (int)(i % wt);
    out[i] = (c < wa) ? A[(long)m * wa + c] : B[(long)m * wb + (c - wa)];
  }
}

// ---------------------------------------------------------------------------
// CSR build, 8-way partitioned atomics.  Partition p = (combined_i >> 8) & 7.
// ---------------------------------------------------------------------------
__global__ void count3_kernel(
    const int* c1, int E1, int* cp1, int* rnk1, int n1,
    const int* c2, int E2, int* cp2, int* rnk2, int n2,
    const int* c3, int E3, int* cp3, int* rnk3, int n3) {
  int total = E1 + E2 + E3;
  for (int i = blockIdx.x * blockDim.x + threadIdx.x; i < total; i += gridDim.x * blockDim.x) {
    int p = (i >> 8) & 7;
    if (i < E1) {
      int d = c1[i]; rnk1[i] = atomicAdd(&cp1[p * n1 + d], 1);
    } else if (i < E1 + E2) {
      int j = i - E1;
      int d = c2[j]; rnk2[j] = atomicAdd(&cp2[p * n2 + d], 1);
    } else {
      int j = i - E1 - E2;
      int d = c3[j]; rnk3[j] = atomicAdd(&cp3[p * n3 + d], 1);
    }
  }
}

__global__ void merge3_kernel(int* cp1, int* c1, int n1,
                              int* cp2, int* c2, int n2,
                              int* cp3, int* c3, int n3) {
  int i = blockIdx.x * blockDim.x + threadIdx.x;
  int total = n1 + n2 + n3;
  if (i >= total) return;
  int *cp, *c; int n, d;
  if (i < n1) { cp = cp1; c = c1; n = n1; d = i; }
  else if (i < n1 + n2) { cp = cp2; c = c2; n = n2; d = i - n1; }
  else { cp = cp3; c = c3; n = n3; d = i - n1 - n2; }
  int s = 0;
#pragma unroll
  for (int p = 0; p < 8; ++p) { int t = cp[p * n + d]; cp[p * n + d] = s; s += t; }
  c[d] = s;
}

__global__ __launch_bounds__(1024) void scan3_kernel(
    const int* cntA, int nA, int* ptrA,
    const int* cntB, int nB, int* ptrB,
    const int* cntC, int nC, int* ptrC) {
  const int* cnt; int n; int* ptr;
  if (blockIdx.x == 0) { cnt = cntA; n = nA; ptr = ptrA; }
  else if (blockIdx.x == 1) { cnt = cntB; n = nB; ptr = ptrB; }
  else { cnt = cntC; n = nC; ptr = ptrC; }
  __shared__ int part[1024];
  int t = threadIdx.x;
  int ch = (n + 1023) / 1024;
  int beg = t * ch, end = min(beg + ch, n);
  int s = 0;
  for (int i = beg; i < end; ++i) s += cnt[i];
  part[t] = s;
  __syncthreads();
  for (int off = 1; off < 1024; off <<= 1) {
    int v = (t >= off) ? part[t - off] : 0;
    __syncthreads();
    part[t] += v;
    __syncthreads();
  }
  int run = (t == 0) ? 0 : part[t - 1];
  for (int i = beg; i < end; ++i) { ptr[i] = run; run += cnt[i]; }
  if (t == 1023) ptr[n] = part[1023];
}

__global__ void scatter3_kernel(
    const int* r1, const int* c1, const float* e1, int E1, const int* p1, const int* cp1, const int* k1, int n1, int* s1, float* a1,
    const int* r2, const int* c2, const float* e2, int E2, const int* p2, const int* cp2, const int* k2, int n2, int* s2, float* a2,
    const int* r3, const int* c3, const float* e3, int E3, const int* p3, const int* cp3, const int* k3, int n3, int* s3, float* a3) {
  int total = E1 + E2 + E3;
  for (int i = blockIdx.x * blockDim.x + threadIdx.x; i < total; i += gridDim.x * blockDim.x) {
    int p = (i >> 8) & 7;
    if (i < E1) {
      int d = c1[i];
      int pos = p1[d] + cp1[p * n1 + d] + k1[i];
      s1[pos] = r1[i]; a1[pos] = e1[i];
    } else if (i < E1 + E2) {
      int j = i - E1;
      int d = c2[j];
      int pos = p2[d] + cp2[p * n2 + d] + k2[j];
      s2[pos] = r2[j]; a2[pos] = e2[j];
    } else {
      int j = i - E1 - E2;
      int d = c3[j];
      int pos = p3[d] + cp3[p * n3 + d] + k3[j];
      s3[pos] = r3[j]; a3[pos] = e3[j];
    }
  }
}

// loop_ea = mean of incoming edge_attr, from contiguous CSR cea
__global__ void leafin_csr2(const int* ptrA, const float* ceaA, int nA, float* leaA,
                            const int* ptrB, const float* ceaB, int nB, float* leaB) {
  int i = blockIdx.x * blockDim.x + threadIdx.x;
  if (i >= nA + nB) return;
  const int* ptr; const float* cea; float* lea; int d;
  if (i < nA) { ptr = ptrA; cea = ceaA; lea = leaA; d = i; }
  else { ptr = ptrB; cea = ceaB; lea = leaB; d = i - nA; }
  int e0 = ptr[d], e1 = ptr[d + 1];
  float s = 0.f;
  for (int e = e0; e < e1; ++e) s += cea[e];
  lea[d] = s / (float)max(e1 - e0, 1);
}

// dot_e[h] = sum_c We[h*64+c] * a_e[h*64+c]; all 5 layers in one launch
__global__ void dote_all_kernel(const float* __restrict__ We0, const float* __restrict__ ae0,
                                const float* __restrict__ We1, const float* __restrict__ ae1,
                                const float* __restrict__ Web, const float* __restrict__ aeb,
                                const float* __restrict__ We2, const float* __restrict__ ae2,
                                const float* __restrict__ We3, const float* __restrict__ ae3,
                                float* __restrict__ dotes) {
  int b = blockIdx.x, t = threadIdx.x;
  const float *We, *ae;
  int n, off;
  switch (b) {
    case 0: We = We0; ae = ae0; n = 256; off = 0; break;
    case 1: We = We1; ae = ae1; n = 256; off = 4; break;
    case 2: We = Web; ae = aeb; n = 64;  off = 8; break;
    case 3: We = We2; ae = ae2; n = 256; off = 12; break;
    default: We = We3; ae = ae3; n = 256; off = 16; break;
  }
  if (t < n) {
    float p = wave_red_sum(We[t] * ae[t]);
    if ((t & 63) == 0) dotes[off + (t >> 6)] = p;
  }
}

struct XSrc { const float* p[5]; int w[5]; int n; };

// ---------------------------------------------------------------------------
// NOUT=64 projection, register-only: NO LDS, NO barriers.  W read per-lane
// coalesced from global (L2-resident, <=73KB).  Wave owns 4 consecutive rows;
// X loads are wave-uniform float4 broadcasts; 16 independent FMA chains.
// Grid = M/16 (M % 16 == 0) -> thousands of waves, ~5 waves/SIMD.
// mode: 0 = bias (skip store if Y null), 1 = bias+relu,
//       2 = final split (mean | softplus+eps)
// ---------------------------------------------------------------------------
__global__ __launch_bounds__(256) void proj64r_kernel(
    XSrc xsrc, int M, int K,
    const float* __restrict__ W, const float* __restrict__ bias, int mode,
    const float* __restrict__ a_s, const float* __restrict__ a_d,
    float* __restrict__ al_s, float* __restrict__ al_d,
    float* __restrict__ Y, float* __restrict__ Y2) {
  int t = threadIdx.x;
  int lane = t & 63;
  long r0 = ((long)blockIdx.x * 4 + (t >> 6)) * 4;   // 4 rows per wave
  if (r0 >= M) return;
  float acc0 = 0.f, acc1 = 0.f, acc2 = 0.f, acc3 = 0.f;
  int kbase = 0;
  for (int s = 0; s < xsrc.n; ++s) {
    const float* Xp = xsrc.p[s];
    int w = xsrc.w[s];
    const float* x0 = Xp + r0 * w;
    const float* x1 = x0 + w;
    const float* x2 = x1 + w;
    const float* x3 = x2 + w;
    const float* Wp = W + (long)kbase * 64 + lane;
    for (int k = 0; k < w; k += 4) {
      float4 a = *(const float4*)(x0 + k);
      float4 b = *(const float4*)(x1 + k);
      float4 c = *(const float4*)(x2 + k);
      float4 d = *(const float4*)(x3 + k);
      float w0 = Wp[(k + 0) * 64];
      float w1 = Wp[(k + 1) * 64];
      float w2 = Wp[(k + 2) * 64];
      float w3 = Wp[(k + 3) * 64];
      acc0 = fmaf(a.x, w0, acc0); acc1 = fmaf(b.x, w0, acc1);
      acc2 = fmaf(c.x, w0, acc2); acc3 = fmaf(d.x, w0, acc3);
      acc0 = fmaf(a.y, w1, acc0); acc1 = fmaf(b.y, w1, acc1);
      acc2 = fmaf(c.y, w1, acc2); acc3 = fmaf(d.y, w1, acc3);
      acc0 = fmaf(a.z, w2, acc0); acc1 = fmaf(b.z, w2, acc1);
      acc2 = fmaf(c.z, w2, acc2); acc3 = fmaf(d.z, w2, acc3);
      acc0 = fmaf(a.w, w3, acc0); acc1 = fmaf(b.w, w3, acc1);
      acc2 = fmaf(c.w, w3, acc2); acc3 = fmaf(d.w, w3, acc3);
    }
    kbase += w;
  }
  float bv = bias ? bias[lane] : 0.f;
  float asv = a_s ? a_s[lane] : 0.f;
  float adv = a_d ? a_d[lane] : 0.f;
  float accs[4] = {acc0, acc1, acc2, acc3};
#pragma unroll
  for (int j = 0; j < 4; ++j) {
    long m = r0 + j;
    float v = accs[j] + bv;
    if (mode == 1) {
      Y[m * 64 + lane] = fmaxf(v, 0.f);
    } else if (mode == 2) {
      if (lane < 32) Y[m * 32 + lane] = v;
      else Y2[m * 32 + (lane - 32)] =
          fmaxf(v, 0.f) + log1pf(__expf(-fabsf(v))) + 1e-6f;
    } else if (Y) {
      Y[m * 64 + lane] = v;
    }
    if (a_s) {
      float s = wave_red_sum(accs[j] * asv);
      if (lane == 0) al_s[m] = s;
    }
    if (a_d) {
      float s = wave_red_sum(accs[j] * adv);
      if (lane == 0) al_d[m] = s;
    }
  }
}

// ---------------------------------------------------------------------------
// NOUT=256 projection (tiled, BR=32): X and W staged in LDS.
// mode: 3 = store bf16 (used for all H=4 hs tables)
// ---------------------------------------------------------------------------
__global__ __launch_bounds__(256) void proj_kernel(
    XSrc xsrc, int M, int K,
    const float* __restrict__ W, const float* __restrict__ bias, int mode,
    const float* __restrict__ a_s, const float* __restrict__ a_d,
    float* __restrict__ al_s, float* __restrict__ al_d,
    float* __restrict__ Y, float* __restrict__ Y2) {
  constexpr int NOUT = 256;
  constexpr int KC = 32;
  constexpr int RPT = 8;
  constexpr int BR = 32;
  constexpr int KCP = 36;
  constexpr int H = 4;
  __shared__ float wl[KC * NOUT];
  __shared__ float xl[BR * KCP];

  int t = threadIdx.x;
  int cg = t & 63, rg = t >> 6;
  int c0 = cg * 4;
  long row0 = (long)blockIdx.x * BR;

  float acc[RPT][4];
#pragma unroll
  for (int r = 0; r < RPT; ++r)
#pragma unroll
    for (int j = 0; j < 4; ++j) acc[r][j] = 0.f;

  for (int k0 = 0; k0 < K; k0 += KC) {
    int kc = min(KC, K - k0);
    int seg = 0; int base = 0;
    while (k0 >= base + xsrc.w[seg]) { base += xsrc.w[seg]; ++seg; }
    const float* Xp = xsrc.p[seg];
    int stride = xsrc.w[seg];
    int kloc = k0 - base;

    __syncthreads();
    {
      const float4* wsrc = (const float4*)(W + (long)k0 * NOUT);
      float4* wdst = (float4*)wl;
      for (int i = t; i < (kc * NOUT) >> 2; i += 256) wdst[i] = wsrc[i];
    }
    for (int i = t; i < BR * 8; i += 256) {
      int r = i >> 3, kq = (i & 7) * 4;
      if (kq < kc) {
        long rr = row0 + r; if (rr >= M) rr = M - 1;
        float4 v = *(const float4*)(Xp + rr * stride + kloc + kq);
        *(float4*)(xl + r * KCP + kq) = v;
      }
    }
    __syncthreads();

    for (int kg = 0; kg < kc; kg += 4) {
      float4 w0 = *(const float4*)(wl + (kg + 0) * NOUT + c0);
      float4 w1 = *(const float4*)(wl + (kg + 1) * NOUT + c0);
      float4 w2 = *(const float4*)(wl + (kg + 2) * NOUT + c0);
      float4 w3 = *(const float4*)(wl + (kg + 3) * NOUT + c0);
      float4 xv[RPT];
#pragma unroll
      for (int r = 0; r < RPT; ++r)
        xv[r] = *(const float4*)(xl + (rg * RPT + r) * KCP + kg);
#pragma unroll
      for (int r = 0; r < RPT; ++r) {
        acc[r][0] = fmaf(xv[r].x, w0.x, acc[r][0]);
        acc[r][1] = fmaf(xv[r].x, w0.y, acc[r][1]);
        acc[r][2] = fmaf(xv[r].x, w0.z, acc[r][2]);
        acc[r][3] = fmaf(xv[r].x, w0.w, acc[r][3]);
        acc[r][0] = fmaf(xv[r].y, w1.x, acc[r][0]);
        acc[r][1] = fmaf(xv[r].y, w1.y, acc[r][1]);
        acc[r][2] = fmaf(xv[r].y, w1.z, acc[r][2]);
        acc[r][3] = fmaf(xv[r].y, w1.w, acc[r][3]);
        acc[r][0] = fmaf(xv[r].z, w2.x, acc[r][0]);
        acc[r][1] = fmaf(xv[r].z, w2.y, acc[r][1]);
        acc[r][2] = fmaf(xv[r].z, w2.z, acc[r][2]);
        acc[r][3] = fmaf(xv[r].z, w2.w, acc[r][3]);
        acc[r][0] = fmaf(xv[r].w, w3.x, acc[r][0]);
        acc[r][1] = fmaf(xv[r].w, w3.y, acc[r][1]);
        acc[r][2] = fmaf(xv[r].w, w3.z, acc[r][2]);
        acc[r][3] = fmaf(xv[r].w, w3.w, acc[r][3]);
      }
    }
  }

  float4 asv = make_float4(0.f, 0.f, 0.f, 0.f);
  float4 adv = make_float4(0.f, 0.f, 0.f, 0.f);
  if (a_s) asv = *(const float4*)(a_s + c0);
  if (a_d) adv = *(const float4*)(a_d + c0);

#pragma unroll
  for (int r = 0; r < RPT; ++r) {
    long m = row0 + (long)rg * RPT + r;
    bool ok = m < M;
    if (ok && mode == 3) {
      ushort4 o;
      o.x = f2bf(acc[r][0]); o.y = f2bf(acc[r][1]);
      o.z = f2bf(acc[r][2]); o.w = f2bf(acc[r][3]);
      *(ushort4*)((unsigned short*)Y + m * NOUT + c0) = o;
    }
    if (a_s) {
      float s = acc[r][0] * asv.x + acc[r][1] * asv.y + acc[r][2] * asv.z + acc[r][3] * asv.w;
      s += __shfl_xor(s, 1); s += __shfl_xor(s, 2);
      s += __shfl_xor(s, 4); s += __shfl_xor(s, 8);
      if (ok && (cg & 15) == 0) al_s[m * H + (c0 >> 6)] = s;
    }
    if (a_d) {
      float s = acc[r][0] * adv.x + acc[r][1] * adv.y + acc[r][2] * adv.z + acc[r][3] * adv.w;
      s += __shfl_xor(s, 1); s += __shfl_xor(s, 2);
      s += __shfl_xor(s, 4); s += __shfl_xor(s, 8);
      if (ok && (cg & 15) == 0) al_d[m * H + (c0 >> 6)] = s;
    }
  }
  (void)bias; (void)Y2;
}

// ---------------------------------------------------------------------------
// GAT pass A: attention weights.  thread = (node, head), h fastest.
// ---------------------------------------------------------------------------
template <int H, bool SELFLOOP>
__global__ void attn_kernel(
    int Nd, const int* __restrict__ dptr, const int* __restrict__ csr_src,
    const float* __restrict__ csr_ea, const float* __restrict__ al_s,
    const float* __restrict__ al_d, const float* __restrict__ dote,
    const float* __restrict__ loop_ea,
    float* __restrict__ alpha, float* __restrict__ aloop, float* __restrict__ invden) {
  int tid = blockIdx.x * blockDim.x + threadIdx.x;
  if (tid >= Nd * H) return;
  int n = tid / H, h = tid % H;
  float ald = al_d[(long)n * H + h];
  float de = dote[h];
  int e0 = dptr[n], e1 = dptr[n + 1];
  float m = -INFINITY;
  for (int e = e0; e < e1; ++e) {
    int src = csr_src[e];
    float l = al_s[(long)src * H + h] + ald + csr_ea[e] * de;
    l = (l > 0.f) ? l : 0.2f * l;
    m = fmaxf(m, l);
  }
  float lloop = 0.f;
  if (SELFLOOP) {
    lloop = al_s[(long)n * H + h] + ald + loop_ea[n] * de;
    lloop = (lloop > 0.f) ? lloop : 0.2f * lloop;
    m = fmaxf(m, lloop);
  }
  float den = 0.f;
  for (int e = e0; e < e1; ++e) {
    int src = csr_src[e];
    float l = al_s[(long)src * H + h] + ald + csr_ea[e] * de;
    l = (l > 0.f) ? l : 0.2f * l;
    float ex = __expf(l - m);
    den += ex;
    alpha[(long)e * H + h] = ex;
  }
  if (SELFLOOP) {
    float ex = __expf(lloop - m);
    den += ex;
    aloop[(long)n * H + h] = ex;
  }
  invden[(long)n * H + h] = 1.f / (den + 1e-16f);
}

// ---------------------------------------------------------------------------
// GAT pass B, H=4 C=64 over bf16 hs (512B rows): one wave per node.
// ---------------------------------------------------------------------------
__device__ __forceinline__ void fma4_bf(float4& a, float al, ushort4 u) {
  a.x = fmaf(al, bf2f(u.x), a.x); a.y = fmaf(al, bf2f(u.y), a.y);
  a.z = fmaf(al, bf2f(u.z), a.z); a.w = fmaf(al, bf2f(u.w), a.w);
}

template <bool SELFLOOP>
__global__ __launch_bounds__(256) void agg4_kernel(
    int Nd, const int* __restrict__ dptr, const int* __restrict__ csr_src,
    const float* __restrict__ alpha, const float* __restrict__ aloop,
    const float* __restrict__ invden, const unsigned short* __restrict__ hs,
    const float* __restrict__ bias, float* __restrict__ out) {
  int wave = threadIdx.x >> 6, lane = threadIdx.x & 63;
  int n = blockIdx.x * 4 + wave;
  if (n >= Nd) return;
  int h = lane >> 4;
  int e0 = dptr[n], e1 = dptr[n + 1];
  float4 a0v = make_float4(0.f, 0.f, 0.f, 0.f);
  float4 a1v = make_float4(0.f, 0.f, 0.f, 0.f);
  int e = e0;
  for (; e + 2 <= e1; e += 2) {
    int s0 = csr_src[e], s1 = csr_src[e + 1];
    float a0 = alpha[(long)e * 4 + h];
    float a1 = alpha[(long)(e + 1) * 4 + h];
    ushort4 u0 = *(const ushort4*)(hs + (long)s0 * 256 + lane * 4);
    ushort4 u1 = *(const ushort4*)(hs + (long)s1 * 256 + lane * 4);
    fma4_bf(a0v, a0, u0);
    fma4_bf(a1v, a1, u1);
  }
  if (e < e1) {
    int s0 = csr_src[e];
    float a0 = alpha[(long)e * 4 + h];
    ushort4 u0 = *(const ushort4*)(hs + (long)s0 * 256 + lane * 4);
    fma4_bf(a0v, a0, u0);
  }
  a0v.x += a1v.x; a0v.y += a1v.y; a0v.z += a1v.z; a0v.w += a1v.w;
  if (SELFLOOP) {
    float a = aloop[(long)n * 4 + h];
    ushort4 u = *(const ushort4*)(hs + (long)n * 256 + lane * 4);
    fma4_bf(a0v, a, u);
  }
  float inv = invden[(long)n * 4 + h];
  a0v.x *= inv; a0v.y *= inv; a0v.z *= inv; a0v.w *= inv;
  a0v.x += __shfl_xor(a0v.x, 16); a0v.y += __shfl_xor(a0v.y, 16);
  a0v.z += __shfl_xor(a0v.z, 16); a0v.w += __shfl_xor(a0v.w, 16);
  a0v.x += __shfl_xor(a0v.x, 32); a0v.y += __shfl_xor(a0v.y, 32);
  a0v.z += __shfl_xor(a0v.z, 32); a0v.w += __shfl_xor(a0v.w, 32);
  if (lane < 16) {
    float4 b = *(const float4*)(bias + lane * 4);
    float4 o;
    o.x = fmaxf(a0v.x * 0.25f + b.x, 0.f);
    o.y = fmaxf(a0v.y * 0.25f + b.y, 0.f);
    o.z = fmaxf(a0v.z * 0.25f + b.z, 0.f);
    o.w = fmaxf(a0v.w * 0.25f + b.w, 0.f);
    *(float4*)(out + (long)n * 64 + lane * 4) = o;
  }
}

// GAT pass B, H=1 C=64 (fp32 hs): wave per node, lane = channel.
__global__ __launch_bounds__(256) void agg1_kernel(
    int Nd, const int* __restrict__ dptr, const int* __restrict__ csr_src,
    const float* __restrict__ alpha, const float* __restrict__ invden,
    const float* __restrict__ hs, const float* __restrict__ bias,
    float* __restrict__ out) {
  int wave = threadIdx.x >> 6, lane = threadIdx.x & 63;
  int n = blockIdx.x * 4 + wave;
  if (n >= Nd) return;
  int e0 = dptr[n], e1 = dptr[n + 1];
  float acc0 = 0.f, acc1 = 0.f;
  int e = e0;
  for (; e + 2 <= e1; e += 2) {
    int s0 = csr_src[e], s1 = csr_src[e + 1];
    acc0 = fmaf(alpha[e], hs[(long)s0 * 64 + lane], acc0);
    acc1 = fmaf(alpha[e + 1], hs[(long)s1 * 64 + lane], acc1);
  }
  if (e < e1) acc0 = fmaf(alpha[e], hs[(long)csr_src[e] * 64 + lane], acc0);
  acc0 += acc1;
  float o = acc0 * invden[n];
  out[(long)n * 64 + lane] = fmaxf(o + bias[lane], 0.f);
}

// ---------------------------------------------------------------------------
extern "C" void kernel_launch(void* const* d_in, const int* in_sizes, int n_in,
                              void* d_out, int out_size, void* d_ws, size_t ws_size,
                              hipStream_t stream) {
  const float* sp_mean = (const float*)d_in[0];
  const float* sp_std  = (const float*)d_in[1];
  const void*  nanmask = d_in[2];
  const float* sp_gen  = (const float*)d_in[3];
  const float* sp_phy  = (const float*)d_in[4];
  const float* spat_x  = (const float*)d_in[5];
  const float* spat_g  = (const float*)d_in[6];
  const int*   ss_ei   = (const int*)d_in[7];
  const float* ss_ea   = (const float*)d_in[8];
  const int*   bip_ei  = (const int*)d_in[9];
  const float* bip_ea  = (const float*)d_in[10];
  const int*   sp_ei   = (const int*)d_in[11];
  const float* sp_ea   = (const float*)d_in[12];
  const float* sg0_W = (const float*)d_in[13]; const float* sg0_as = (const float*)d_in[14];
  const float* sg0_ad = (const float*)d_in[15]; const float* sg0_ae = (const float*)d_in[16];
  const float* sg0_We = (const float*)d_in[17]; const float* sg0_b = (const float*)d_in[18];
  const float* sg1_W = (const float*)d_in[19]; const float* sg1_as = (const float*)d_in[20];
  const float* sg1_ad = (const float*)d_in[21]; const float* sg1_ae = (const float*)d_in[22];
  const float* sg1_We = (const float*)d_in[23]; const float* sg1_b = (const float*)d_in[24];
  const float* pg0_W = (const float*)d_in[25]; const float* pg0_as = (const float*)d_in[26];
  const float* pg0_ad = (const float*)d_in[27]; const float* pg0_ae = (const float*)d_in[28];
  const float* pg0_We = (const float*)d_in[29]; const float* pg0_b = (const float*)d_in[30];
  const float* pg1_W = (const float*)d_in[31]; const float* pg1_as = (const float*)d_in[32];
  const float* pg1_ad = (const float*)d_in[33]; const float* pg1_ae = (const float*)d_in[34];
  const float* pg1_We = (const float*)d_in[35]; const float* pg1_b = (const float*)d_in[36];
  const float* bp_Ws = (const float*)d_in[37]; const float* bp_Wd = (const float*)d_in[38];
  const float* bp_as = (const float*)d_in[39]; const float* bp_ad = (const float*)d_in[40];
  const float* bp_ae = (const float*)d_in[41]; const float* bp_We = (const float*)d_in[42];
  const float* bp_b  = (const float*)d_in[43];
  const float* sl_W  = (const float*)d_in[44]; const float* sl_b  = (const float*)d_in[45];
  const float* fc_W  = (const float*)d_in[46]; const float* fc_b  = (const float*)d_in[47];

  // ---- workspace layout ----
  char* wsb = (char*)d_ws;
  size_t off = 0;
  auto A = [&](size_t nbytes) -> void* {
    void* p = wsb + off;
    off += (nbytes + 255) & ~(size_t)255;
    return p;
  };
  // --- zeroed region (single memset): partitioned counters ---
  int* ss_cp = (int*)A((size_t)8 * NSPAT * 4);
  int* bp_cp = (int*)A((size_t)8 * NSP * 4);
  int* pp_cp = (int*)A((size_t)8 * NSP * 4);
  size_t zbytes = off;
  // --- rest ---
  int*   ss_cnt = (int*)A((NSPAT + 1) * 4);
  int*   bp_cnt = (int*)A((NSP + 1) * 4);
  int*   pp_cnt = (int*)A((NSP + 1) * 4);
  float* dotes = (float*)A(5 * 4 * sizeof(float));
  float* alS   = (float*)A((size_t)NSP * 4 * 4);
  float* alD   = (float*)A((size_t)NSP * 4 * 4);
  float* spc96 = (float*)A((size_t)NSP * 96 * 4);
  float* sp_in = (float*)A((size_t)NSP * 64 * 4);
  float* h0    = (float*)A((size_t)NSPAT * 16 * 4);
  float* h_a   = (float*)A((size_t)NSPAT * 64 * 4);
  float* h_b   = (float*)A((size_t)NSPAT * 64 * 4);
  float* HS    = (float*)A((size_t)NSP * 256 * 4);   // bf16 hs rows
  float* sts   = (float*)A((size_t)NSP * 64 * 4);
  float* x1    = (float*)A((size_t)NSP * 64 * 4);
  int*   ss_ptr = (int*)A((NSPAT + 1) * 4);
  int*   ss_src = (int*)A((size_t)ESS * 4);
  float* ss_cea = (float*)A((size_t)ESS * 4);
  int*   ss_rnk = (int*)A((size_t)ESS * 4);
  float* ss_lea = (float*)A((size_t)NSPAT * 4);
  int*   bp_ptr = (int*)A((NSP + 1) * 4);
  int*   bp_src = (int*)A((size_t)EBIP * 4);
  float* bp_cea = (float*)A((size_t)EBIP * 4);
  int*   bp_rnk = (int*)A((size_t)EBIP * 4);
  int*   pp_ptr = (int*)A((NSP + 1) * 4);
  int*   pp_src = (int*)A((size_t)ESP * 4);
  float* pp_cea = (float*)A((size_t)ESP * 4);
  int*   pp_rnk = (int*)A((size_t)ESP * 4);
  float* pp_lea = (float*)A((size_t)NSP * 4);
  float* ss_alpha = (float*)A((size_t)ESS * 4 * 4);
  float* ss_aloop = (float*)A((size_t)NSPAT * 4 * 4);
  float* ss_invd  = (float*)A((size_t)NSPAT * 4 * 4);
  float* bp_alpha = (float*)A((size_t)EBIP * 4);
  float* bp_invd  = (float*)A((size_t)NSP * 4);
  float* pp_alpha = (float*)A((size_t)ESP * 4 * 4);
  float* pp_aloop = (float*)A((size_t)NSP * 4 * 4);
  float* pp_invd  = (float*)A((size_t)NSP * 4 * 4);
  (void)ws_size; (void)in_sizes; (void)n_in; (void)out_size;

  const int TB = 256;
  hipMemsetAsync(wsb, 0, zbytes, stream);

  // ---- graph builds: partitioned count -> merge -> scan -> scatter ----
  count3_kernel<<<cdiv_host(ESS + EBIP + ESP, TB), TB, 0, stream>>>(
      ss_ei + ESS, ESS, ss_cp, ss_rnk, NSPAT,
      bip_ei + EBIP, EBIP, bp_cp, bp_rnk, NSP,
      sp_ei + ESP, ESP, pp_cp, pp_rnk, NSP);
  merge3_kernel<<<cdiv_host(NSPAT + NSP + NSP, TB), TB, 0, stream>>>(
      ss_cp, ss_cnt, NSPAT, bp_cp, bp_cnt, NSP, pp_cp, pp_cnt, NSP);
  scan3_kernel<<<3, 1024, 0, stream>>>(ss_cnt, NSPAT, ss_ptr, bp_cnt, NSP, bp_ptr, pp_cnt, NSP, pp_ptr);
  scatter3_kernel<<<cdiv_host(ESS + EBIP + ESP, TB), TB, 0, stream>>>(
      ss_ei, ss_ei + ESS, ss_ea, ESS, ss_ptr, ss_cp, ss_rnk, NSPAT, ss_src, ss_cea,
      bip_ei, bip_ei + EBIP, bip_ea, EBIP, bp_ptr, bp_cp, bp_rnk, NSP, bp_src, bp_cea,
      sp_ei, sp_ei + ESP, sp_ea, ESP, pp_ptr, pp_cp, pp_rnk, NSP, pp_src, pp_cea);
  leafin_csr2<<<cdiv_host(NSPAT + NSP, TB), TB, 0, stream>>>(
      ss_ptr, ss_cea, NSPAT, ss_lea, pp_ptr, pp_cea, NSP, pp_lea);

  dote_all_kernel<<<5, 256, 0, stream>>>(sg0_We, sg0_ae, sg1_We, sg1_ae, bp_We, bp_ae,
                                         pg0_We, pg0_ae, pg1_We, pg1_ae, dotes);

  // ---- species input MLP ----
  build_spcat96<<<cdiv_host((long)NSP * 96, TB), TB, 0, stream>>>(sp_mean, sp_std, nanmask, spc96);
  {
    XSrc xs{}; xs.p[0] = spc96; xs.w[0] = 96; xs.p[1] = sp_gen; xs.w[1] = 64;
    xs.p[2] = sp_phy; xs.w[2] = 128; xs.n = 3;
    proj64r_kernel<<<NSP / 16, TB, 0, stream>>>(xs, NSP, 288, sl_W, sl_b, 1,
        nullptr, nullptr, nullptr, nullptr, sp_in, nullptr);
  }

  // ---- spatial GNN ----
  concat2_kernel<<<cdiv_host((long)NSPAT * 16, TB), TB, 0, stream>>>(spat_x, 12, spat_g, 4, NSPAT, h0);
  {
    XSrc xs{}; xs.p[0] = h0; xs.w[0] = 16; xs.n = 1;
    proj_kernel<<<cdiv_host(NSPAT, 32), TB, 0, stream>>>(xs, NSPAT, 16, sg0_W, nullptr, 3,
        sg0_as, sg0_ad, alS, alD, HS, nullptr);
  }
  attn_kernel<4, true><<<cdiv_host((long)NSPAT * 4, TB), TB, 0, stream>>>(
      NSPAT, ss_ptr, ss_src, ss_cea, alS, alD, dotes + 0, ss_lea, ss_alpha, ss_aloop, ss_invd);
  agg4_kernel<true><<<cdiv_host(NSPAT, 4), TB, 0, stream>>>(
      NSPAT, ss_ptr, ss_src, ss_alpha, ss_aloop, ss_invd, (const unsigned short*)HS, sg0_b, h_a);
  {
    XSrc xs{}; xs.p[0] = h_a; xs.w[0] = 64; xs.n = 1;
    proj_kernel<<<cdiv_host(NSPAT, 32), TB, 0, stream>>>(xs, NSPAT, 64, sg1_W, nullptr, 3,
        sg1_as, sg1_ad, alS, alD, HS, nullptr);
  }
  attn_kernel<4, true><<<cdiv_host((long)NSPAT * 4, TB), TB, 0, stream>>>(
      NSPAT, ss_ptr, ss_src, ss_cea, alS, alD, dotes + 4, ss_lea, ss_alpha, ss_aloop, ss_invd);
  agg4_kernel<true><<<cdiv_host(NSPAT, 4), TB, 0, stream>>>(
      NSPAT, ss_ptr, ss_src, ss_alpha, ss_aloop, ss_invd, (const unsigned short*)HS, sg1_b, h_b);

  // ---- bipartite GAT (spatial -> species), H=1, concat ----
  {
    XSrc xs{}; xs.p[0] = h_b; xs.w[0] = 64; xs.n = 1;
    proj64r_kernel<<<NSPAT / 16, TB, 0, stream>>>(xs, NSPAT, 64, bp_Ws, nullptr, 0,
        bp_as, nullptr, alS, nullptr, h_a, nullptr);   // h_a := hs_src (fp32)
  }
  {
    XSrc xs{}; xs.p[0] = sp_gen; xs.w[0] = 64; xs.p[1] = sp_phy; xs.w[1] = 128; xs.n = 2;
    proj64r_kernel<<<NSP / 16, TB, 0, stream>>>(xs, NSP, 192, bp_Wd, nullptr, 0,
        nullptr, bp_ad, nullptr, alD, nullptr, nullptr);   // only al_d needed
  }
  attn_kernel<1, false><<<cdiv_host(NSP, TB), TB, 0, stream>>>(
      NSP, bp_ptr, bp_src, bp_cea, alS, alD, dotes + 8, nullptr, bp_alpha, nullptr, bp_invd);
  agg1_kernel<<<cdiv_host(NSP, 4), TB, 0, stream>>>(
      NSP, bp_ptr, bp_src, bp_alpha, bp_invd, h_a, bp_b, sts);

  // ---- species GNN ----
  {
    XSrc xs{}; xs.p[0] = sts; xs.w[0] = 64; xs.p[1] = sp_in; xs.w[1] = 64; xs.n = 2;
    proj_kernel<<<cdiv_host(NSP, 32), TB, 0, stream>>>(xs, NSP, 128, pg0_W, nullptr, 3,
        pg0_as, pg0_ad, alS, alD, HS, nullptr);
  }
  attn_kernel<4, true><<<cdiv_host((long)NSP * 4, TB), TB, 0, stream>>>(
      NSP, pp_ptr, pp_src, pp_cea, alS, alD, dotes + 12, pp_lea, pp_alpha, pp_aloop, pp_invd);
  agg4_kernel<true><<<cdiv_host(NSP, 4), TB, 0, stream>>>(
      NSP, pp_ptr, pp_src, pp_alpha, pp_aloop, pp_invd, (const unsigned short*)HS, pg0_b, x1);
  {
    XSrc xs{}; xs.p[0] = x1; xs.w[0] = 64; xs.n = 1;
    proj_kernel<<<cdiv_host(NSP, 32), TB, 0, stream>>>(xs, NSP, 64, pg1_W, nullptr, 3,
        pg1_as, pg1_ad, alS, alD, HS, nullptr);
  }
  attn_kernel<4, true><<<cdiv_host((long)NSP * 4, TB), TB, 0, stream>>>(
      NSP, pp_ptr, pp_src, pp_cea, alS, alD, dotes + 16, pp_lea, pp_alpha, pp_aloop, pp_invd);
  agg4_kernel<true><<<cdiv_host(NSP, 4), TB, 0, stream>>>(
      NSP, pp_ptr, pp_src, pp_alpha, pp_aloop, pp_invd, (const unsigned short*)HS, pg1_b, sts);

  // ---- final linear fused with split/softplus ----
  {
    XSrc xs{}; xs.p[0] = sts; xs.w[0] = 64; xs.n = 1;
    proj64r_kernel<<<NSP / 16, TB, 0, stream>>>(xs, NSP, 64, fc_W, fc_b, 2,
        nullptr, nullptr, nullptr, nullptr, (float*)d_out, (float*)d_out + (long)NSP * 32);
  }
}

// Round 8
// 620.236 us; speedup vs baseline: 1.1876x; 1.1191x over previous
//
#include <hip/hip_runtime.h>
#include <hip/hip_bf16.h>

#define NSP   20000
#define NSPAT 10000
#define ESS   160000
#define EBIP  320000
#define ESP   320000

static inline int cdiv_host(long a, long b) { return (int)((a + b - 1) / b); }

__device__ __forceinline__ float wave_red_sum(float p) {
#pragma unroll
  for (int m = 32; m >= 1; m >>= 1) p += __shfl_xor(p, m, 64);
  return p;
}

__device__ __forceinline__ float bf2f(unsigned short u) {
  return __uint_as_float(((unsigned int)u) << 16);
}
__device__ __forceinline__ unsigned short f2bf(float f) {
  unsigned int u = __float_as_uint(f);
  unsigned int r = (u + 0x7FFF + ((u >> 16) & 1)) >> 16;  // RN-even
  return (unsigned short)r;
}

// ---------------------------------------------------------------------------
// species 96-wide prefix: [mean(32) | std(32) | vis(32)]; mask format
// detected per-block (0 = int32 {0,1}, 1 = bytes {0,1}, 2 = float {0,1.0f})
// ---------------------------------------------------------------------------
__global__ void build_spcat96(const float* __restrict__ mean, const float* __restrict__ stdv,
                              const void* __restrict__ mask,
                              float* __restrict__ out) {
  __shared__ int smode;
  if (threadIdx.x == 0) {
    const unsigned int* m = (const unsigned int*)mask;
    int allint = 1, allfloat = 1;
    for (int i = 0; i < 256; ++i) {
      unsigned int w = m[i];
      if (w != 0u && w != 1u) allint = 0;
      if (w != 0u && w != 0x3f800000u) allfloat = 0;
    }
    smode = allint ? 0 : (allfloat ? 2 : 1);
  }
  __syncthreads();
  int mode = smode;
  const long total = (long)NSP * 96;
  for (long i = (long)blockIdx.x * blockDim.x + threadIdx.x; i < total;
       i += (long)gridDim.x * blockDim.x) {
    int n = (int)(i / 96), c = (int)(i % 96);
    float v;
    if (c < 32) v = mean[(long)n * 32 + c];
    else if (c < 64) v = stdv[(long)n * 32 + (c - 32)];
    else {
      long j = (long)n * 32 + (c - 64);
      int mv;
      if (mode == 0) mv = ((const int*)mask)[j];
      else if (mode == 2) mv = (((const float*)mask)[j] != 0.0f);
      else mv = (int)((const unsigned char*)mask)[j];
      v = mv ? 0.f : 1.f;   // vis = ~mask
    }
    out[i] = v;
  }
}

__global__ void concat2_kernel(const float* __restrict__ A, int wa,
                               const float* __restrict__ B, int wb,
                               int M, float* __restrict__ out) {
  const int wt = wa + wb;
  const long total = (long)M * wt;
  for (long i = (long)blockIdx.x * blockDim.x + threadIdx.x; i < total;
       i += (long)gridDim.x * blockDim.x) {
    int m = (int)(i / wt), c = (int)(i % wt);
    out[i] = (c < wa) ? A[(long)m * wa + c] : B[(long)m * wb + (c - wa)];
  }
}

// ---------------------------------------------------------------------------
// CSR build, 8-way partitioned atomics.  Partition p = (combined_i >> 8) & 7.
// ---------------------------------------------------------------------------
__global__ void count3_kernel(
    const int* c1, int E1, int* cp1, int* rnk1, int n1,
    const int* c2, int E2, int* cp2, int* rnk2, int n2,
    const int* c3, int E3, int* cp3, int* rnk3, int n3) {
  int total = E1 + E2 + E3;
  for (int i = blockIdx.x * blockDim.x + threadIdx.x; i < total; i += gridDim.x * blockDim.x) {
    int p = (i >> 8) & 7;
    if (i < E1) {
      int d = c1[i]; rnk1[i] = atomicAdd(&cp1[p * n1 + d], 1);
    } else if (i < E1 + E2) {
      int j = i - E1;
      int d = c2[j]; rnk2[j] = atomicAdd(&cp2[p * n2 + d], 1);
    } else {
      int j = i - E1 - E2;
      int d = c3[j]; rnk3[j] = atomicAdd(&cp3[p * n3 + d], 1);
    }
  }
}

__global__ void merge3_kernel(int* cp1, int* c1, int n1,
                              int* cp2, int* c2, int n2,
                              int* cp3, int* c3, int n3) {
  int i = blockIdx.x * blockDim.x + threadIdx.x;
  int total = n1 + n2 + n3;
  if (i >= total) return;
  int *cp, *c; int n, d;
  if (i < n1) { cp = cp1; c = c1; n = n1; d = i; }
  else if (i < n1 + n2) { cp = cp2; c = c2; n = n2; d = i - n1; }
  else { cp = cp3; c = c3; n = n3; d = i - n1 - n2; }
  int s = 0;
#pragma unroll
  for (int p = 0; p < 8; ++p) { int t = cp[p * n + d]; cp[p * n + d] = s; s += t; }
  c[d] = s;
}

__global__ __launch_bounds__(1024) void scan3_kernel(
    const int* cntA, int nA, int* ptrA,
    const int* cntB, int nB, int* ptrB,
    const int* cntC, int nC, int* ptrC) {
  const int* cnt; int n; int* ptr;
  if (blockIdx.x == 0) { cnt = cntA; n = nA; ptr = ptrA; }
  else if (blockIdx.x == 1) { cnt = cntB; n = nB; ptr = ptrB; }
  else { cnt = cntC; n = nC; ptr = ptrC; }
  __shared__ int part[1024];
  int t = threadIdx.x;
  int ch = (n + 1023) / 1024;
  int beg = t * ch, end = min(beg + ch, n);
  int s = 0;
  for (int i = beg; i < end; ++i) s += cnt[i];
  part[t] = s;
  __syncthreads();
  for (int off = 1; off < 1024; off <<= 1) {
    int v = (t >= off) ? part[t - off] : 0;
    __syncthreads();
    part[t] += v;
    __syncthreads();
  }
  int run = (t == 0) ? 0 : part[t - 1];
  for (int i = beg; i < end; ++i) { ptr[i] = run; run += cnt[i]; }
  if (t == 1023) ptr[n] = part[1023];
}

__global__ void scatter3_kernel(
    const int* r1, const int* c1, const float* e1, int E1, const int* p1, const int* cp1, const int* k1, int n1, int* s1, float* a1,
    const int* r2, const int* c2, const float* e2, int E2, const int* p2, const int* cp2, const int* k2, int n2, int* s2, float* a2,
    const int* r3, const int* c3, const float* e3, int E3, const int* p3, const int* cp3, const int* k3, int n3, int* s3, float* a3) {
  int total = E1 + E2 + E3;
  for (int i = blockIdx.x * blockDim.x + threadIdx.x; i < total; i += gridDim.x * blockDim.x) {
    int p = (i >> 8) & 7;
    if (i < E1) {
      int d = c1[i];
      int pos = p1[d] + cp1[p * n1 + d] + k1[i];
      s1[pos] = r1[i]; a1[pos] = e1[i];
    } else if (i < E1 + E2) {
      int j = i - E1;
      int d = c2[j];
      int pos = p2[d] + cp2[p * n2 + d] + k2[j];
      s2[pos] = r2[j]; a2[pos] = e2[j];
    } else {
      int j = i - E1 - E2;
      int d = c3[j];
      int pos = p3[d] + cp3[p * n3 + d] + k3[j];
      s3[pos] = r3[j]; a3[pos] = e3[j];
    }
  }
}

// loop_ea = mean of incoming edge_attr, from contiguous CSR cea
__global__ void leafin_csr2(const int* ptrA, const float* ceaA, int nA, float* leaA,
                            const int* ptrB, const float* ceaB, int nB, float* leaB) {
  int i = blockIdx.x * blockDim.x + threadIdx.x;
  if (i >= nA + nB) return;
  const int* ptr; const float* cea; float* lea; int d;
  if (i < nA) { ptr = ptrA; cea = ceaA; lea = leaA; d = i; }
  else { ptr = ptrB; cea = ceaB; lea = leaB; d = i - nA; }
  int e0 = ptr[d], e1 = ptr[d + 1];
  float s = 0.f;
  for (int e = e0; e < e1; ++e) s += cea[e];
  lea[d] = s / (float)max(e1 - e0, 1);
}

// dot_e[h] = sum_c We[h*64+c] * a_e[h*64+c]; all 5 layers in one launch
__global__ void dote_all_kernel(const float* __restrict__ We0, const float* __restrict__ ae0,
                                const float* __restrict__ We1, const float* __restrict__ ae1,
                                const float* __restrict__ Web, const float* __restrict__ aeb,
                                const float* __restrict__ We2, const float* __restrict__ ae2,
                                const float* __restrict__ We3, const float* __restrict__ ae3,
                                float* __restrict__ dotes) {
  int b = blockIdx.x, t = threadIdx.x;
  const float *We, *ae;
  int n, off;
  switch (b) {
    case 0: We = We0; ae = ae0; n = 256; off = 0; break;
    case 1: We = We1; ae = ae1; n = 256; off = 4; break;
    case 2: We = Web; ae = aeb; n = 64;  off = 8; break;
    case 3: We = We2; ae = ae2; n = 256; off = 12; break;
    default: We = We3; ae = ae3; n = 256; off = 16; break;
  }
  if (t < n) {
    float p = wave_red_sum(We[t] * ae[t]);
    if ((t & 63) == 0) dotes[off + (t >> 6)] = p;
  }
}

struct XSrc { const float* p[5]; int w[5]; int n; };

// ---------------------------------------------------------------------------
// NOUT=64 projection, tiled: BR=32 rows/block (grid = M/32, large), KC=32.
// Per thread: 4 cols x 2 rows (16 col-groups x 16 row-groups).  W chunk 8KB +
// X chunk 4.6KB staged in LDS via burst coalesced loads (high MLP).
// All K and segment widths are multiples of 32.
// mode: 0 = bias (skip store if Y null), 1 = bias+relu,
//       2 = final split (mean | softplus+eps).  a_s/a_d: H=1 dots.
// ---------------------------------------------------------------------------
__global__ __launch_bounds__(256) void proj64_kernel(
    XSrc xsrc, int M, int K,
    const float* __restrict__ W, const float* __restrict__ bias, int mode,
    const float* __restrict__ a_s, const float* __restrict__ a_d,
    float* __restrict__ al_s, float* __restrict__ al_d,
    float* __restrict__ Y, float* __restrict__ Y2) {
  constexpr int KC = 32;
  constexpr int BR = 32;
  constexpr int KCP = 36;
  __shared__ float wl[KC * 64];
  __shared__ float xl[BR * KCP];

  int t = threadIdx.x;
  int cg = t & 15, rg = t >> 4;   // 16 col-groups, 16 row-groups (2 rows each)
  int c0 = cg * 4;
  long row0 = (long)blockIdx.x * BR;

  float acc[2][4];
#pragma unroll
  for (int r = 0; r < 2; ++r)
#pragma unroll
    for (int j = 0; j < 4; ++j) acc[r][j] = 0.f;

  for (int k0 = 0; k0 < K; k0 += KC) {
    int seg = 0; int base = 0;
    while (k0 >= base + xsrc.w[seg]) { base += xsrc.w[seg]; ++seg; }
    const float* Xp = xsrc.p[seg];
    int stride = xsrc.w[seg];
    int kloc = k0 - base;

    __syncthreads();
    // stage W chunk: 512 float4, 2 per thread
    {
      const float4* ws = (const float4*)(W + (long)k0 * 64);
      float4* wd = (float4*)wl;
      wd[t] = ws[t];
      wd[t + 256] = ws[t + 256];
    }
    // stage X chunk: 256 float4, 1 per thread (row = t/8, quad = t%8)
    {
      int r = t >> 3, kq = (t & 7) * 4;
      long rr = row0 + r; if (rr >= M) rr = M - 1;
      float4 v = *(const float4*)(Xp + rr * stride + kloc + kq);
      *(float4*)(xl + r * KCP + kq) = v;
    }
    __syncthreads();

    for (int kg = 0; kg < KC; kg += 4) {
      float4 w0 = *(const float4*)(wl + (kg + 0) * 64 + c0);
      float4 w1 = *(const float4*)(wl + (kg + 1) * 64 + c0);
      float4 w2 = *(const float4*)(wl + (kg + 2) * 64 + c0);
      float4 w3 = *(const float4*)(wl + (kg + 3) * 64 + c0);
#pragma unroll
      for (int r = 0; r < 2; ++r) {
        float4 xv = *(const float4*)(xl + (rg * 2 + r) * KCP + kg);
        acc[r][0] = fmaf(xv.x, w0.x, acc[r][0]);
        acc[r][1] = fmaf(xv.x, w0.y, acc[r][1]);
        acc[r][2] = fmaf(xv.x, w0.z, acc[r][2]);
        acc[r][3] = fmaf(xv.x, w0.w, acc[r][3]);
        acc[r][0] = fmaf(xv.y, w1.x, acc[r][0]);
        acc[r][1] = fmaf(xv.y, w1.y, acc[r][1]);
        acc[r][2] = fmaf(xv.y, w1.z, acc[r][2]);
        acc[r][3] = fmaf(xv.y, w1.w, acc[r][3]);
        acc[r][0] = fmaf(xv.z, w2.x, acc[r][0]);
        acc[r][1] = fmaf(xv.z, w2.y, acc[r][1]);
        acc[r][2] = fmaf(xv.z, w2.z, acc[r][2]);
        acc[r][3] = fmaf(xv.z, w2.w, acc[r][3]);
        acc[r][0] = fmaf(xv.w, w3.x, acc[r][0]);
        acc[r][1] = fmaf(xv.w, w3.y, acc[r][1]);
        acc[r][2] = fmaf(xv.w, w3.z, acc[r][2]);
        acc[r][3] = fmaf(xv.w, w3.w, acc[r][3]);
      }
    }
  }

  float4 bv = make_float4(0.f, 0.f, 0.f, 0.f);
  float4 asv = make_float4(0.f, 0.f, 0.f, 0.f);
  float4 adv = make_float4(0.f, 0.f, 0.f, 0.f);
  if (bias) bv = *(const float4*)(bias + c0);
  if (a_s) asv = *(const float4*)(a_s + c0);
  if (a_d) adv = *(const float4*)(a_d + c0);

#pragma unroll
  for (int r = 0; r < 2; ++r) {
    long m = row0 + rg * 2 + r;
    bool ok = m < M;
    float v0 = acc[r][0] + bv.x, v1 = acc[r][1] + bv.y;
    float v2 = acc[r][2] + bv.z, v3 = acc[r][3] + bv.w;
    if (mode == 1) {
      if (ok)
        *(float4*)(Y + m * 64 + c0) = make_float4(
            fmaxf(v0, 0.f), fmaxf(v1, 0.f), fmaxf(v2, 0.f), fmaxf(v3, 0.f));
    } else if (mode == 2) {
      if (ok) {
        if (c0 < 32) {
          *(float4*)(Y + m * 32 + c0) = make_float4(v0, v1, v2, v3);
        } else {
          float4 o;
          o.x = fmaxf(v0, 0.f) + log1pf(__expf(-fabsf(v0))) + 1e-6f;
          o.y = fmaxf(v1, 0.f) + log1pf(__expf(-fabsf(v1))) + 1e-6f;
          o.z = fmaxf(v2, 0.f) + log1pf(__expf(-fabsf(v2))) + 1e-6f;
          o.w = fmaxf(v3, 0.f) + log1pf(__expf(-fabsf(v3))) + 1e-6f;
          *(float4*)(Y2 + m * 32 + (c0 - 32)) = o;
        }
      }
    } else if (ok && Y) {
      *(float4*)(Y + m * 64 + c0) = make_float4(v0, v1, v2, v3);
    }
    if (a_s) {
      float s = acc[r][0] * asv.x + acc[r][1] * asv.y + acc[r][2] * asv.z + acc[r][3] * asv.w;
      s += __shfl_xor(s, 1); s += __shfl_xor(s, 2);
      s += __shfl_xor(s, 4); s += __shfl_xor(s, 8);
      if (ok && cg == 0) al_s[m] = s;
    }
    if (a_d) {
      float s = acc[r][0] * adv.x + acc[r][1] * adv.y + acc[r][2] * adv.z + acc[r][3] * adv.w;
      s += __shfl_xor(s, 1); s += __shfl_xor(s, 2);
      s += __shfl_xor(s, 4); s += __shfl_xor(s, 8);
      if (ok && cg == 0) al_d[m] = s;
    }
  }
}

// ---------------------------------------------------------------------------
// NOUT=256 projection (tiled, BR=32): X and W staged in LDS.
// mode: 3 = store bf16 (used for all H=4 hs tables)
// ---------------------------------------------------------------------------
__global__ __launch_bounds__(256) void proj_kernel(
    XSrc xsrc, int M, int K,
    const float* __restrict__ W, const float* __restrict__ bias, int mode,
    const float* __restrict__ a_s, const float* __restrict__ a_d,
    float* __restrict__ al_s, float* __restrict__ al_d,
    float* __restrict__ Y, float* __restrict__ Y2) {
  constexpr int NOUT = 256;
  constexpr int KC = 32;
  constexpr int RPT = 8;
  constexpr int BR = 32;
  constexpr int KCP = 36;
  constexpr int H = 4;
  __shared__ float wl[KC * NOUT];
  __shared__ float xl[BR * KCP];

  int t = threadIdx.x;
  int cg = t & 63, rg = t >> 6;
  int c0 = cg * 4;
  long row0 = (long)blockIdx.x * BR;

  float acc[RPT][4];
#pragma unroll
  for (int r = 0; r < RPT; ++r)
#pragma unroll
    for (int j = 0; j < 4; ++j) acc[r][j] = 0.f;

  for (int k0 = 0; k0 < K; k0 += KC) {
    int kc = min(KC, K - k0);
    int seg = 0; int base = 0;
    while (k0 >= base + xsrc.w[seg]) { base += xsrc.w[seg]; ++seg; }
    const float* Xp = xsrc.p[seg];
    int stride = xsrc.w[seg];
    int kloc = k0 - base;

    __syncthreads();
    {
      const float4* wsrc = (const float4*)(W + (long)k0 * NOUT);
      float4* wdst = (float4*)wl;
      for (int i = t; i < (kc * NOUT) >> 2; i += 256) wdst[i] = wsrc[i];
    }
    for (int i = t; i < BR * 8; i += 256) {
      int r = i >> 3, kq = (i & 7) * 4;
      if (kq < kc) {
        long rr = row0 + r; if (rr >= M) rr = M - 1;
        float4 v = *(const float4*)(Xp + rr * stride + kloc + kq);
        *(float4*)(xl + r * KCP + kq) = v;
      }
    }
    __syncthreads();

    for (int kg = 0; kg < kc; kg += 4) {
      float4 w0 = *(const float4*)(wl + (kg + 0) * NOUT + c0);
      float4 w1 = *(const float4*)(wl + (kg + 1) * NOUT + c0);
      float4 w2 = *(const float4*)(wl + (kg + 2) * NOUT + c0);
      float4 w3 = *(const float4*)(wl + (kg + 3) * NOUT + c0);
      float4 xv[RPT];
#pragma unroll
      for (int r = 0; r < RPT; ++r)
        xv[r] = *(const float4*)(xl + (rg * RPT + r) * KCP + kg);
#pragma unroll
      for (int r = 0; r < RPT; ++r) {
        acc[r][0] = fmaf(xv[r].x, w0.x, acc[r][0]);
        acc[r][1] = fmaf(xv[r].x, w0.y, acc[r][1]);
        acc[r][2] = fmaf(xv[r].x, w0.z, acc[r][2]);
        acc[r][3] = fmaf(xv[r].x, w0.w, acc[r][3]);
        acc[r][0] = fmaf(xv[r].y, w1.x, acc[r][0]);
        acc[r][1] = fmaf(xv[r].y, w1.y, acc[r][1]);
        acc[r][2] = fmaf(xv[r].y, w1.z, acc[r][2]);
        acc[r][3] = fmaf(xv[r].y, w1.w, acc[r][3]);
        acc[r][0] = fmaf(xv[r].z, w2.x, acc[r][0]);
        acc[r][1] = fmaf(xv[r].z, w2.y, acc[r][1]);
        acc[r][2] = fmaf(xv[r].z, w2.z, acc[r][2]);
        acc[r][3] = fmaf(xv[r].z, w2.w, acc[r][3]);
        acc[r][0] = fmaf(xv[r].w, w3.x, acc[r][0]);
        acc[r][1] = fmaf(xv[r].w, w3.y, acc[r][1]);
        acc[r][2] = fmaf(xv[r].w, w3.z, acc[r][2]);
        acc[r][3] = fmaf(xv[r].w, w3.w, acc[r][3]);
      }
    }
  }

  float4 asv = make_float4(0.f, 0.f, 0.f, 0.f);
  float4 adv = make_float4(0.f, 0.f, 0.f, 0.f);
  if (a_s) asv = *(const float4*)(a_s + c0);
  if (a_d) adv = *(const float4*)(a_d + c0);

#pragma unroll
  for (int r = 0; r < RPT; ++r) {
    long m = row0 + (long)rg * RPT + r;
    bool ok = m < M;
    if (ok && mode == 3) {
      ushort4 o;
      o.x = f2bf(acc[r][0]); o.y = f2bf(acc[r][1]);
      o.z = f2bf(acc[r][2]); o.w = f2bf(acc[r][3]);
      *(ushort4*)((unsigned short*)Y + m * NOUT + c0) = o;
    }
    if (a_s) {
      float s = acc[r][0] * asv.x + acc[r][1] * asv.y + acc[r][2] * asv.z + acc[r][3] * asv.w;
      s += __shfl_xor(s, 1); s += __shfl_xor(s, 2);
      s += __shfl_xor(s, 4); s += __shfl_xor(s, 8);
      if (ok && (cg & 15) == 0) al_s[m * H + (c0 >> 6)] = s;
    }
    if (a_d) {
      float s = acc[r][0] * adv.x + acc[r][1] * adv.y + acc[r][2] * adv.z + acc[r][3] * adv.w;
      s += __shfl_xor(s, 1); s += __shfl_xor(s, 2);
      s += __shfl_xor(s, 4); s += __shfl_xor(s, 8);
      if (ok && (cg & 15) == 0) al_d[m * H + (c0 >> 6)] = s;
    }
  }
  (void)bias; (void)Y2;
}

// ---------------------------------------------------------------------------
// GAT pass A: attention weights.  thread = (node, head), h fastest.
// ---------------------------------------------------------------------------
template <int H, bool SELFLOOP>
__global__ void attn_kernel(
    int Nd, const int* __restrict__ dptr, const int* __restrict__ csr_src,
    const float* __restrict__ csr_ea, const float* __restrict__ al_s,
    const float* __restrict__ al_d, const float* __restrict__ dote,
    const float* __restrict__ loop_ea,
    float* __restrict__ alpha, float* __restrict__ aloop, float* __restrict__ invden) {
  int tid = blockIdx.x * blockDim.x + threadIdx.x;
  if (tid >= Nd * H) return;
  int n = tid / H, h = tid % H;
  float ald = al_d[(long)n * H + h];
  float de = dote[h];
  int e0 = dptr[n], e1 = dptr[n + 1];
  float m = -INFINITY;
  for (int e = e0; e < e1; ++e) {
    int src = csr_src[e];
    float l = al_s[(long)src * H + h] + ald + csr_ea[e] * de;
    l = (l > 0.f) ? l : 0.2f * l;
    m = fmaxf(m, l);
  }
  float lloop = 0.f;
  if (SELFLOOP) {
    lloop = al_s[(long)n * H + h] + ald + loop_ea[n] * de;
    lloop = (lloop > 0.f) ? lloop : 0.2f * lloop;
    m = fmaxf(m, lloop);
  }
  float den = 0.f;
  for (int e = e0; e < e1; ++e) {
    int src = csr_src[e];
    float l = al_s[(long)src * H + h] + ald + csr_ea[e] * de;
    l = (l > 0.f) ? l : 0.2f * l;
    float ex = __expf(l - m);
    den += ex;
    alpha[(long)e * H + h] = ex;
  }
  if (SELFLOOP) {
    float ex = __expf(lloop - m);
    den += ex;
    aloop[(long)n * H + h] = ex;
  }
  invden[(long)n * H + h] = 1.f / (den + 1e-16f);
}

// ---------------------------------------------------------------------------
// GAT pass B, H=4 C=64 over bf16 hs (512B rows): one wave per node.
// ---------------------------------------------------------------------------
__device__ __forceinline__ void fma4_bf(float4& a, float al, ushort4 u) {
  a.x = fmaf(al, bf2f(u.x), a.x); a.y = fmaf(al, bf2f(u.y), a.y);
  a.z = fmaf(al, bf2f(u.z), a.z); a.w = fmaf(al, bf2f(u.w), a.w);
}

template <bool SELFLOOP>
__global__ __launch_bounds__(256) void agg4_kernel(
    int Nd, const int* __restrict__ dptr, const int* __restrict__ csr_src,
    const float* __restrict__ alpha, const float* __restrict__ aloop,
    const float* __restrict__ invden, const unsigned short* __restrict__ hs,
    const float* __restrict__ bias, float* __restrict__ out) {
  int wave = threadIdx.x >> 6, lane = threadIdx.x & 63;
  int n = blockIdx.x * 4 + wave;
  if (n >= Nd) return;
  int h = lane >> 4;
  int e0 = dptr[n], e1 = dptr[n + 1];
  float4 a0v = make_float4(0.f, 0.f, 0.f, 0.f);
  float4 a1v = make_float4(0.f, 0.f, 0.f, 0.f);
  int e = e0;
  for (; e + 2 <= e1; e += 2) {
    int s0 = csr_src[e], s1 = csr_src[e + 1];
    float a0 = alpha[(long)e * 4 + h];
    float a1 = alpha[(long)(e + 1) * 4 + h];
    ushort4 u0 = *(const ushort4*)(hs + (long)s0 * 256 + lane * 4);
    ushort4 u1 = *(const ushort4*)(hs + (long)s1 * 256 + lane * 4);
    fma4_bf(a0v, a0, u0);
    fma4_bf(a1v, a1, u1);
  }
  if (e < e1) {
    int s0 = csr_src[e];
    float a0 = alpha[(long)e * 4 + h];
    ushort4 u0 = *(const ushort4*)(hs + (long)s0 * 256 + lane * 4);
    fma4_bf(a0v, a0, u0);
  }
  a0v.x += a1v.x; a0v.y += a1v.y; a0v.z += a1v.z; a0v.w += a1v.w;
  if (SELFLOOP) {
    float a = aloop[(long)n * 4 + h];
    ushort4 u = *(const ushort4*)(hs + (long)n * 256 + lane * 4);
    fma4_bf(a0v, a, u);
  }
  float inv = invden[(long)n * 4 + h];
  a0v.x *= inv; a0v.y *= inv; a0v.z *= inv; a0v.w *= inv;
  a0v.x += __shfl_xor(a0v.x, 16); a0v.y += __shfl_xor(a0v.y, 16);
  a0v.z += __shfl_xor(a0v.z, 16); a0v.w += __shfl_xor(a0v.w, 16);
  a0v.x += __shfl_xor(a0v.x, 32); a0v.y += __shfl_xor(a0v.y, 32);
  a0v.z += __shfl_xor(a0v.z, 32); a0v.w += __shfl_xor(a0v.w, 32);
  if (lane < 16) {
    float4 b = *(const float4*)(bias + lane * 4);
    float4 o;
    o.x = fmaxf(a0v.x * 0.25f + b.x, 0.f);
    o.y = fmaxf(a0v.y * 0.25f + b.y, 0.f);
    o.z = fmaxf(a0v.z * 0.25f + b.z, 0.f);
    o.w = fmaxf(a0v.w * 0.25f + b.w, 0.f);
    *(float4*)(out + (long)n * 64 + lane * 4) = o;
  }
}

// GAT pass B, H=1 C=64 (fp32 hs): wave per node, lane = channel.
__global__ __launch_bounds__(256) void agg1_kernel(
    int Nd, const int* __restrict__ dptr, const int* __restrict__ csr_src,
    const float* __restrict__ alpha, const float* __restrict__ invden,
    const float* __restrict__ hs, const float* __restrict__ bias,
    float* __restrict__ out) {
  int wave = threadIdx.x >> 6, lane = threadIdx.x & 63;
  int n = blockIdx.x * 4 + wave;
  if (n >= Nd) return;
  int e0 = dptr[n], e1 = dptr[n + 1];
  float acc0 = 0.f, acc1 = 0.f;
  int e = e0;
  for (; e + 2 <= e1; e += 2) {
    int s0 = csr_src[e], s1 = csr_src[e + 1];
    acc0 = fmaf(alpha[e], hs[(long)s0 * 64 + lane], acc0);
    acc1 = fmaf(alpha[e + 1], hs[(long)s1 * 64 + lane], acc1);
  }
  if (e < e1) acc0 = fmaf(alpha[e], hs[(long)csr_src[e] * 64 + lane], acc0);
  acc0 += acc1;
  float o = acc0 * invden[n];
  out[(long)n * 64 + lane] = fmaxf(o + bias[lane], 0.f);
}

// ---------------------------------------------------------------------------
extern "C" void kernel_launch(void* const* d_in, const int* in_sizes, int n_in,
                              void* d_out, int out_size, void* d_ws, size_t ws_size,
                              hipStream_t stream) {
  const float* sp_mean = (const float*)d_in[0];
  const float* sp_std  = (const float*)d_in[1];
  const void*  nanmask = d_in[2];
  const float* sp_gen  = (const float*)d_in[3];
  const float* sp_phy  = (const float*)d_in[4];
  const float* spat_x  = (const float*)d_in[5];
  const float* spat_g  = (const float*)d_in[6];
  const int*   ss_ei   = (const int*)d_in[7];
  const float* ss_ea   = (const float*)d_in[8];
  const int*   bip_ei  = (const int*)d_in[9];
  const float* bip_ea  = (const float*)d_in[10];
  const int*   sp_ei   = (const int*)d_in[11];
  const float* sp_ea   = (const float*)d_in[12];
  const float* sg0_W = (const float*)d_in[13]; const float* sg0_as = (const float*)d_in[14];
  const float* sg0_ad = (const float*)d_in[15]; const float* sg0_ae = (const float*)d_in[16];
  const float* sg0_We = (const float*)d_in[17]; const float* sg0_b = (const float*)d_in[18];
  const float* sg1_W = (const float*)d_in[19]; const float* sg1_as = (const float*)d_in[20];
  const float* sg1_ad = (const float*)d_in[21]; const float* sg1_ae = (const float*)d_in[22];
  const float* sg1_We = (const float*)d_in[23]; const float* sg1_b = (const float*)d_in[24];
  const float* pg0_W = (const float*)d_in[25]; const float* pg0_as = (const float*)d_in[26];
  const float* pg0_ad = (const float*)d_in[27]; const float* pg0_ae = (const float*)d_in[28];
  const float* pg0_We = (const float*)d_in[29]; const float* pg0_b = (const float*)d_in[30];
  const float* pg1_W = (const float*)d_in[31]; const float* pg1_as = (const float*)d_in[32];
  const float* pg1_ad = (const float*)d_in[33]; const float* pg1_ae = (const float*)d_in[34];
  const float* pg1_We = (const float*)d_in[35]; const float* pg1_b = (const float*)d_in[36];
  const float* bp_Ws = (const float*)d_in[37]; const float* bp_Wd = (const float*)d_in[38];
  const float* bp_as = (const float*)d_in[39]; const float* bp_ad = (const float*)d_in[40];
  const float* bp_ae = (const float*)d_in[41]; const float* bp_We = (const float*)d_in[42];
  const float* bp_b  = (const float*)d_in[43];
  const float* sl_W  = (const float*)d_in[44]; const float* sl_b  = (const float*)d_in[45];
  const float* fc_W  = (const float*)d_in[46]; const float* fc_b  = (const float*)d_in[47];

  // ---- workspace layout ----
  char* wsb = (char*)d_ws;
  size_t off = 0;
  auto A = [&](size_t nbytes) -> void* {
    void* p = wsb + off;
    off += (nbytes + 255) & ~(size_t)255;
    return p;
  };
  // --- zeroed region (single memset): partitioned counters ---
  int* ss_cp = (int*)A((size_t)8 * NSPAT * 4);
  int* bp_cp = (int*)A((size_t)8 * NSP * 4);
  int* pp_cp = (int*)A((size_t)8 * NSP * 4);
  size_t zbytes = off;
  // --- rest ---
  int*   ss_cnt = (int*)A((NSPAT + 1) * 4);
  int*   bp_cnt = (int*)A((NSP + 1) * 4);
  int*   pp_cnt = (int*)A((NSP + 1) * 4);
  float* dotes = (float*)A(5 * 4 * sizeof(float));
  float* alS   = (float*)A((size_t)NSP * 4 * 4);
  float* alD   = (float*)A((size_t)NSP * 4 * 4);
  float* spc96 = (float*)A((size_t)NSP * 96 * 4);
  float* sp_in = (float*)A((size_t)NSP * 64 * 4);
  float* h0    = (float*)A((size_t)NSPAT * 16 * 4);
  float* h_a   = (float*)A((size_t)NSPAT * 64 * 4);
  float* h_b   = (float*)A((size_t)NSPAT * 64 * 4);
  float* HS    = (float*)A((size_t)NSP * 256 * 4);   // bf16 hs rows
  float* sts   = (float*)A((size_t)NSP * 64 * 4);
  float* x1    = (float*)A((size_t)NSP * 64 * 4);
  int*   ss_ptr = (int*)A((NSPAT + 1) * 4);
  int*   ss_src = (int*)A((size_t)ESS * 4);
  float* ss_cea = (float*)A((size_t)ESS * 4);
  int*   ss_rnk = (int*)A((size_t)ESS * 4);
  float* ss_lea = (float*)A((size_t)NSPAT * 4);
  int*   bp_ptr = (int*)A((NSP + 1) * 4);
  int*   bp_src = (int*)A((size_t)EBIP * 4);
  float* bp_cea = (float*)A((size_t)EBIP * 4);
  int*   bp_rnk = (int*)A((size_t)EBIP * 4);
  int*   pp_ptr = (int*)A((NSP + 1) * 4);
  int*   pp_src = (int*)A((size_t)ESP * 4);
  float* pp_cea = (float*)A((size_t)ESP * 4);
  int*   pp_rnk = (int*)A((size_t)ESP * 4);
  float* pp_lea = (float*)A((size_t)NSP * 4);
  float* ss_alpha = (float*)A((size_t)ESS * 4 * 4);
  float* ss_aloop = (float*)A((size_t)NSPAT * 4 * 4);
  float* ss_invd  = (float*)A((size_t)NSPAT * 4 * 4);
  float* bp_alpha = (float*)A((size_t)EBIP * 4);
  float* bp_invd  = (float*)A((size_t)NSP * 4);
  float* pp_alpha = (float*)A((size_t)ESP * 4 * 4);
  float* pp_aloop = (float*)A((size_t)NSP * 4 * 4);
  float* pp_invd  = (float*)A((size_t)NSP * 4 * 4);
  (void)ws_size; (void)in_sizes; (void)n_in; (void)out_size;

  const int TB = 256;
  hipMemsetAsync(wsb, 0, zbytes, stream);

  // ---- graph builds: partitioned count -> merge -> scan -> scatter ----
  count3_kernel<<<cdiv_host(ESS + EBIP + ESP, TB), TB, 0, stream>>>(
      ss_ei + ESS, ESS, ss_cp, ss_rnk, NSPAT,
      bip_ei + EBIP, EBIP, bp_cp, bp_rnk, NSP,
      sp_ei + ESP, ESP, pp_cp, pp_rnk, NSP);
  merge3_kernel<<<cdiv_host(NSPAT + NSP + NSP, TB), TB, 0, stream>>>(
      ss_cp, ss_cnt, NSPAT, bp_cp, bp_cnt, NSP, pp_cp, pp_cnt, NSP);
  scan3_kernel<<<3, 1024, 0, stream>>>(ss_cnt, NSPAT, ss_ptr, bp_cnt, NSP, bp_ptr, pp_cnt, NSP, pp_ptr);
  scatter3_kernel<<<cdiv_host(ESS + EBIP + ESP, TB), TB, 0, stream>>>(
      ss_ei, ss_ei + ESS, ss_ea, ESS, ss_ptr, ss_cp, ss_rnk, NSPAT, ss_src, ss_cea,
      bip_ei, bip_ei + EBIP, bip_ea, EBIP, bp_ptr, bp_cp, bp_rnk, NSP, bp_src, bp_cea,
      sp_ei, sp_ei + ESP, sp_ea, ESP, pp_ptr, pp_cp, pp_rnk, NSP, pp_src, pp_cea);
  leafin_csr2<<<cdiv_host(NSPAT + NSP, TB), TB, 0, stream>>>(
      ss_ptr, ss_cea, NSPAT, ss_lea, pp_ptr, pp_cea, NSP, pp_lea);

  dote_all_kernel<<<5, 256, 0, stream>>>(sg0_We, sg0_ae, sg1_We, sg1_ae, bp_We, bp_ae,
                                         pg0_We, pg0_ae, pg1_We, pg1_ae, dotes);

  // ---- species input MLP ----
  build_spcat96<<<cdiv_host((long)NSP * 96, TB), TB, 0, stream>>>(sp_mean, sp_std, nanmask, spc96);
  {
    XSrc xs{}; xs.p[0] = spc96; xs.w[0] = 96; xs.p[1] = sp_gen; xs.w[1] = 64;
    xs.p[2] = sp_phy; xs.w[2] = 128; xs.n = 3;
    proj64_kernel<<<cdiv_host(NSP, 32), TB, 0, stream>>>(xs, NSP, 288, sl_W, sl_b, 1,
        nullptr, nullptr, nullptr, nullptr, sp_in, nullptr);
  }

  // ---- spatial GNN ----
  concat2_kernel<<<cdiv_host((long)NSPAT * 16, TB), TB, 0, stream>>>(spat_x, 12, spat_g, 4, NSPAT, h0);
  {
    XSrc xs{}; xs.p[0] = h0; xs.w[0] = 16; xs.n = 1;
    proj_kernel<<<cdiv_host(NSPAT, 32), TB, 0, stream>>>(xs, NSPAT, 16, sg0_W, nullptr, 3,
        sg0_as, sg0_ad, alS, alD, HS, nullptr);
  }
  attn_kernel<4, true><<<cdiv_host((long)NSPAT * 4, TB), TB, 0, stream>>>(
      NSPAT, ss_ptr, ss_src, ss_cea, alS, alD, dotes + 0, ss_lea, ss_alpha, ss_aloop, ss_invd);
  agg4_kernel<true><<<cdiv_host(NSPAT, 4), TB, 0, stream>>>(
      NSPAT, ss_ptr, ss_src, ss_alpha, ss_aloop, ss_invd, (const unsigned short*)HS, sg0_b, h_a);
  {
    XSrc xs{}; xs.p[0] = h_a; xs.w[0] = 64; xs.n = 1;
    proj_kernel<<<cdiv_host(NSPAT, 32), TB, 0, stream>>>(xs, NSPAT, 64, sg1_W, nullptr, 3,
        sg1_as, sg1_ad, alS, alD, HS, nullptr);
  }
  attn_kernel<4, true><<<cdiv_host((long)NSPAT * 4, TB), TB, 0, stream>>>(
      NSPAT, ss_ptr, ss_src, ss_cea, alS, alD, dotes + 4, ss_lea, ss_alpha, ss_aloop, ss_invd);
  agg4_kernel<true><<<cdiv_host(NSPAT, 4), TB, 0, stream>>>(
      NSPAT, ss_ptr, ss_src, ss_alpha, ss_aloop, ss_invd, (const unsigned short*)HS, sg1_b, h_b);

  // ---- bipartite GAT (spatial -> species), H=1, concat ----
  {
    XSrc xs{}; xs.p[0] = h_b; xs.w[0] = 64; xs.n = 1;
    proj64_kernel<<<cdiv_host(NSPAT, 32), TB, 0, stream>>>(xs, NSPAT, 64, bp_Ws, nullptr, 0,
        bp_as, nullptr, alS, nullptr, h_a, nullptr);   // h_a := hs_src (fp32)
  }
  {
    XSrc xs{}; xs.p[0] = sp_gen; xs.w[0] = 64; xs.p[1] = sp_phy; xs.w[1] = 128; xs.n = 2;
    proj64_kernel<<<cdiv_host(NSP, 32), TB, 0, stream>>>(xs, NSP, 192, bp_Wd, nullptr, 0,
        nullptr, bp_ad, nullptr, alD, nullptr, nullptr);   // only al_d needed
  }
  attn_kernel<1, false><<<cdiv_host(NSP, TB), TB, 0, stream>>>(
      NSP, bp_ptr, bp_src, bp_cea, alS, alD, dotes + 8, nullptr, bp_alpha, nullptr, bp_invd);
  agg1_kernel<<<cdiv_host(NSP, 4), TB, 0, stream>>>(
      NSP, bp_ptr, bp_src, bp_alpha, bp_invd, h_a, bp_b, sts);

  // ---- species GNN ----
  {
    XSrc xs{}; xs.p[0] = sts; xs.w[0] = 64; xs.p[1] = sp_in; xs.w[1] = 64; xs.n = 2;
    proj_kernel<<<cdiv_host(NSP, 32), TB, 0, stream>>>(xs, NSP, 128, pg0_W, nullptr, 3,
        pg0_as, pg0_ad, alS, alD, HS, nullptr);
  }
  attn_kernel<4, true><<<cdiv_host((long)NSP * 4, TB), TB, 0, stream>>>(
      NSP, pp_ptr, pp_src, pp_cea, alS, alD, dotes + 12, pp_lea, pp_alpha, pp_aloop, pp_invd);
  agg4_kernel<true><<<cdiv_host(NSP, 4), TB, 0, stream>>>(
      NSP, pp_ptr, pp_src, pp_alpha, pp_aloop, pp_invd, (const unsigned short*)HS, pg0_b, x1);
  {
    XSrc xs{}; xs.p[0] = x1; xs.w[0] = 64; xs.n = 1;
    proj_kernel<<<cdiv_host(NSP, 32), TB, 0, stream>>>(xs, NSP, 64, pg1_W, nullptr, 3,
        pg1_as, pg1_ad, alS, alD, HS, nullptr);
  }
  attn_kernel<4, true><<<cdiv_host((long)NSP * 4, TB), TB, 0, stream>>>(
      NSP, pp_ptr, pp_src, pp_cea, alS, alD, dotes + 16, pp_lea, pp_alpha, pp_aloop, pp_invd);
  agg4_kernel<true><<<cdiv_host(NSP, 4), TB, 0, stream>>>(
      NSP, pp_ptr, pp_src, pp_alpha, pp_aloop, pp_invd, (const unsigned short*)HS, pg1_b, sts);

  // ---- final linear fused with split/softplus ----
  {
    XSrc xs{}; xs.p[0] = sts; xs.w[0] = 64; xs.n = 1;
    proj64_kernel<<<cdiv_host(NSP, 32), TB, 0, stream>>>(xs, NSP, 64, fc_W, fc_b, 2,
        nullptr, nullptr, nullptr, nullptr, (float*)d_out, (float*)d_out + (long)NSP * 32);
  }
}

// Round 9
// 604.224 us; speedup vs baseline: 1.2190x; 1.0265x over previous
//
#include <hip/hip_runtime.h>
#include <hip/hip_bf16.h>

#define NSP   20000
#define NSPAT 10000
#define ESS   160000
#define EBIP  320000
#define ESP   320000

static inline int cdiv_host(long a, long b) { return (int)((a + b - 1) / b); }

__device__ __forceinline__ float wave_red_sum(float p) {
#pragma unroll
  for (int m = 32; m >= 1; m >>= 1) p += __shfl_xor(p, m, 64);
  return p;
}

__device__ __forceinline__ float bf2f(unsigned short u) {
  return __uint_as_float(((unsigned int)u) << 16);
}
__device__ __forceinline__ unsigned short f2bf(float f) {
  unsigned int u = __float_as_uint(f);
  unsigned int r = (u + 0x7FFF + ((u >> 16) & 1)) >> 16;  // RN-even
  return (unsigned short)r;
}

// ---------------------------------------------------------------------------
// combined prep: spc96 = [mean|std|vis] (NSP*96) and h0 = [spat_x|spat_g]
// (NSPAT*16).  Mask mode from *flag (0=int32, 1=bytes, 2=float).
// ---------------------------------------------------------------------------
__global__ void build_pre_kernel(const float* __restrict__ mean, const float* __restrict__ stdv,
                                 const void* __restrict__ mask, const int* __restrict__ flag,
                                 const float* __restrict__ sx, const float* __restrict__ sg,
                                 float* __restrict__ spc96, float* __restrict__ h0) {
  const long totA = (long)NSP * 96;
  const long totB = (long)NSPAT * 16;
  int mode = *flag;
  for (long i = (long)blockIdx.x * blockDim.x + threadIdx.x; i < totA + totB;
       i += (long)gridDim.x * blockDim.x) {
    if (i < totA) {
      int n = (int)(i / 96), c = (int)(i % 96);
      float v;
      if (c < 32) v = mean[(long)n * 32 + c];
      else if (c < 64) v = stdv[(long)n * 32 + (c - 32)];
      else {
        long j = (long)n * 32 + (c - 64);
        int mv;
        if (mode == 0) mv = ((const int*)mask)[j];
        else if (mode == 2) mv = (((const float*)mask)[j] != 0.0f);
        else mv = (int)((const unsigned char*)mask)[j];
        v = mv ? 0.f : 1.f;   // vis = ~mask
      }
      spc96[i] = v;
    } else {
      long k = i - totA;
      int n = (int)(k / 16), c = (int)(k % 16);
      h0[k] = (c < 12) ? sx[(long)n * 12 + c] : sg[(long)n * 4 + (c - 12)];
    }
  }
}

// ---------------------------------------------------------------------------
// CSR build, 8-way partitioned atomics.  Partition p = (combined_i >> 8) & 7.
// ---------------------------------------------------------------------------
__global__ void count3_kernel(
    const int* c1, int E1, int* cp1, int* rnk1, int n1,
    const int* c2, int E2, int* cp2, int* rnk2, int n2,
    const int* c3, int E3, int* cp3, int* rnk3, int n3) {
  int total = E1 + E2 + E3;
  for (int i = blockIdx.x * blockDim.x + threadIdx.x; i < total; i += gridDim.x * blockDim.x) {
    int p = (i >> 8) & 7;
    if (i < E1) {
      int d = c1[i]; rnk1[i] = atomicAdd(&cp1[p * n1 + d], 1);
    } else if (i < E1 + E2) {
      int j = i - E1;
      int d = c2[j]; rnk2[j] = atomicAdd(&cp2[p * n2 + d], 1);
    } else {
      int j = i - E1 - E2;
      int d = c3[j]; rnk3[j] = atomicAdd(&cp3[p * n3 + d], 1);
    }
  }
}

__global__ void merge3_kernel(int* cp1, int* c1, int n1,
                              int* cp2, int* c2, int n2,
                              int* cp3, int* c3, int n3) {
  int i = blockIdx.x * blockDim.x + threadIdx.x;
  int total = n1 + n2 + n3;
  if (i >= total) return;
  int *cp, *c; int n, d;
  if (i < n1) { cp = cp1; c = c1; n = n1; d = i; }
  else if (i < n1 + n2) { cp = cp2; c = c2; n = n2; d = i - n1; }
  else { cp = cp3; c = c3; n = n3; d = i - n1 - n2; }
  int s = 0;
#pragma unroll
  for (int p = 0; p < 8; ++p) { int t = cp[p * n + d]; cp[p * n + d] = s; s += t; }
  c[d] = s;
}

__global__ __launch_bounds__(1024) void scan3_kernel(
    const int* cntA, int nA, int* ptrA,
    const int* cntB, int nB, int* ptrB,
    const int* cntC, int nC, int* ptrC) {
  const int* cnt; int n; int* ptr;
  if (blockIdx.x == 0) { cnt = cntA; n = nA; ptr = ptrA; }
  else if (blockIdx.x == 1) { cnt = cntB; n = nB; ptr = ptrB; }
  else { cnt = cntC; n = nC; ptr = ptrC; }
  __shared__ int part[1024];
  int t = threadIdx.x;
  int ch = (n + 1023) / 1024;
  int beg = t * ch, end = min(beg + ch, n);
  int s = 0;
  for (int i = beg; i < end; ++i) s += cnt[i];
  part[t] = s;
  __syncthreads();
  for (int off = 1; off < 1024; off <<= 1) {
    int v = (t >= off) ? part[t - off] : 0;
    __syncthreads();
    part[t] += v;
    __syncthreads();
  }
  int run = (t == 0) ? 0 : part[t - 1];
  for (int i = beg; i < end; ++i) { ptr[i] = run; run += cnt[i]; }
  if (t == 1023) ptr[n] = part[1023];
}

__global__ void scatter3_kernel(
    const int* r1, const int* c1, const float* e1, int E1, const int* p1, const int* cp1, const int* k1, int n1, int* s1, float* a1,
    const int* r2, const int* c2, const float* e2, int E2, const int* p2, const int* cp2, const int* k2, int n2, int* s2, float* a2,
    const int* r3, const int* c3, const float* e3, int E3, const int* p3, const int* cp3, const int* k3, int n3, int* s3, float* a3) {
  int total = E1 + E2 + E3;
  for (int i = blockIdx.x * blockDim.x + threadIdx.x; i < total; i += gridDim.x * blockDim.x) {
    int p = (i >> 8) & 7;
    if (i < E1) {
      int d = c1[i];
      int pos = p1[d] + cp1[p * n1 + d] + k1[i];
      s1[pos] = r1[i]; a1[pos] = e1[i];
    } else if (i < E1 + E2) {
      int j = i - E1;
      int d = c2[j];
      int pos = p2[d] + cp2[p * n2 + d] + k2[j];
      s2[pos] = r2[j]; a2[pos] = e2[j];
    } else {
      int j = i - E1 - E2;
      int d = c3[j];
      int pos = p3[d] + cp3[p * n3 + d] + k3[j];
      s3[pos] = r3[j]; a3[pos] = e3[j];
    }
  }
}

// loop_ea = mean of incoming edge_attr, from contiguous CSR cea
__global__ void leafin_csr2(const int* ptrA, const float* ceaA, int nA, float* leaA,
                            const int* ptrB, const float* ceaB, int nB, float* leaB) {
  int i = blockIdx.x * blockDim.x + threadIdx.x;
  if (i >= nA + nB) return;
  const int* ptr; const float* cea; float* lea; int d;
  if (i < nA) { ptr = ptrA; cea = ceaA; lea = leaA; d = i; }
  else { ptr = ptrB; cea = ceaB; lea = leaB; d = i - nA; }
  int e0 = ptr[d], e1 = ptr[d + 1];
  float s = 0.f;
  for (int e = e0; e < e1; ++e) s += cea[e];
  lea[d] = s / (float)max(e1 - e0, 1);
}

// dot_e[h] per layer (blocks 0..4) + mask-format detect (block 5, 64 lanes)
__global__ void dote_all_kernel(const float* __restrict__ We0, const float* __restrict__ ae0,
                                const float* __restrict__ We1, const float* __restrict__ ae1,
                                const float* __restrict__ Web, const float* __restrict__ aeb,
                                const float* __restrict__ We2, const float* __restrict__ ae2,
                                const float* __restrict__ We3, const float* __restrict__ ae3,
                                const unsigned int* __restrict__ mask,
                                float* __restrict__ dotes, int* __restrict__ flag) {
  int b = blockIdx.x, t = threadIdx.x;
  if (b == 5) {
    if (t < 64) {
      unsigned int w0 = mask[t], w1 = mask[t + 64], w2 = mask[t + 128], w3 = mask[t + 192];
      bool ai = (w0 <= 1u) && (w1 <= 1u) && (w2 <= 1u) && (w3 <= 1u);
      auto okf = [](unsigned int w) { return w == 0u || w == 0x3f800000u; };
      bool af = okf(w0) && okf(w1) && okf(w2) && okf(w3);
      unsigned long long bi = __ballot(ai), bf = __ballot(af);
      if (t == 0) *flag = (bi == ~0ull) ? 0 : ((bf == ~0ull) ? 2 : 1);
    }
    return;
  }
  const float *We, *ae;
  int n, off;
  switch (b) {
    case 0: We = We0; ae = ae0; n = 256; off = 0; break;
    case 1: We = We1; ae = ae1; n = 256; off = 4; break;
    case 2: We = Web; ae = aeb; n = 64;  off = 8; break;
    case 3: We = We2; ae = ae2; n = 256; off = 12; break;
    default: We = We3; ae = ae3; n = 256; off = 16; break;
  }
  if (t < n) {
    float p = wave_red_sum(We[t] * ae[t]);
    if ((t & 63) == 0) dotes[off + (t >> 6)] = p;
  }
}

struct XSrc { const float* p[5]; int w[5]; int n; };

// ---------------------------------------------------------------------------
// NOUT=64 projection, tiled: BR=32 rows/block, KC=32.  4 cols x 2 rows per
// thread.  mode: 0 = bias (skip store if Y null), 1 = bias+relu,
// 2 = final split (mean | softplus+eps).  a_s/a_d: H=1 dots.
// ---------------------------------------------------------------------------
__global__ __launch_bounds__(256) void proj64_kernel(
    XSrc xsrc, int M, int K,
    const float* __restrict__ W, const float* __restrict__ bias, int mode,
    const float* __restrict__ a_s, const float* __restrict__ a_d,
    float* __restrict__ al_s, float* __restrict__ al_d,
    float* __restrict__ Y, float* __restrict__ Y2) {
  constexpr int KC = 32;
  constexpr int BR = 32;
  constexpr int KCP = 36;
  __shared__ float wl[KC * 64];
  __shared__ float xl[BR * KCP];

  int t = threadIdx.x;
  int cg = t & 15, rg = t >> 4;
  int c0 = cg * 4;
  long row0 = (long)blockIdx.x * BR;

  float acc[2][4];
#pragma unroll
  for (int r = 0; r < 2; ++r)
#pragma unroll
    for (int j = 0; j < 4; ++j) acc[r][j] = 0.f;

  for (int k0 = 0; k0 < K; k0 += KC) {
    int seg = 0; int base = 0;
    while (k0 >= base + xsrc.w[seg]) { base += xsrc.w[seg]; ++seg; }
    const float* Xp = xsrc.p[seg];
    int stride = xsrc.w[seg];
    int kloc = k0 - base;

    __syncthreads();
    {
      const float4* ws = (const float4*)(W + (long)k0 * 64);
      float4* wd = (float4*)wl;
      wd[t] = ws[t];
      wd[t + 256] = ws[t + 256];
    }
    {
      int r = t >> 3, kq = (t & 7) * 4;
      long rr = row0 + r; if (rr >= M) rr = M - 1;
      float4 v = *(const float4*)(Xp + rr * stride + kloc + kq);
      *(float4*)(xl + r * KCP + kq) = v;
    }
    __syncthreads();

    for (int kg = 0; kg < KC; kg += 4) {
      float4 w0 = *(const float4*)(wl + (kg + 0) * 64 + c0);
      float4 w1 = *(const float4*)(wl + (kg + 1) * 64 + c0);
      float4 w2 = *(const float4*)(wl + (kg + 2) * 64 + c0);
      float4 w3 = *(const float4*)(wl + (kg + 3) * 64 + c0);
#pragma unroll
      for (int r = 0; r < 2; ++r) {
        float4 xv = *(const float4*)(xl + (rg * 2 + r) * KCP + kg);
        acc[r][0] = fmaf(xv.x, w0.x, acc[r][0]);
        acc[r][1] = fmaf(xv.x, w0.y, acc[r][1]);
        acc[r][2] = fmaf(xv.x, w0.z, acc[r][2]);
        acc[r][3] = fmaf(xv.x, w0.w, acc[r][3]);
        acc[r][0] = fmaf(xv.y, w1.x, acc[r][0]);
        acc[r][1] = fmaf(xv.y, w1.y, acc[r][1]);
        acc[r][2] = fmaf(xv.y, w1.z, acc[r][2]);
        acc[r][3] = fmaf(xv.y, w1.w, acc[r][3]);
        acc[r][0] = fmaf(xv.z, w2.x, acc[r][0]);
        acc[r][1] = fmaf(xv.z, w2.y, acc[r][1]);
        acc[r][2] = fmaf(xv.z, w2.z, acc[r][2]);
        acc[r][3] = fmaf(xv.z, w2.w, acc[r][3]);
        acc[r][0] = fmaf(xv.w, w3.x, acc[r][0]);
        acc[r][1] = fmaf(xv.w, w3.y, acc[r][1]);
        acc[r][2] = fmaf(xv.w, w3.z, acc[r][2]);
        acc[r][3] = fmaf(xv.w, w3.w, acc[r][3]);
      }
    }
  }

  float4 bv = make_float4(0.f, 0.f, 0.f, 0.f);
  float4 asv = make_float4(0.f, 0.f, 0.f, 0.f);
  float4 adv = make_float4(0.f, 0.f, 0.f, 0.f);
  if (bias) bv = *(const float4*)(bias + c0);
  if (a_s) asv = *(const float4*)(a_s + c0);
  if (a_d) adv = *(const float4*)(a_d + c0);

#pragma unroll
  for (int r = 0; r < 2; ++r) {
    long m = row0 + rg * 2 + r;
    bool ok = m < M;
    float v0 = acc[r][0] + bv.x, v1 = acc[r][1] + bv.y;
    float v2 = acc[r][2] + bv.z, v3 = acc[r][3] + bv.w;
    if (mode == 1) {
      if (ok)
        *(float4*)(Y + m * 64 + c0) = make_float4(
            fmaxf(v0, 0.f), fmaxf(v1, 0.f), fmaxf(v2, 0.f), fmaxf(v3, 0.f));
    } else if (mode == 2) {
      if (ok) {
        if (c0 < 32) {
          *(float4*)(Y + m * 32 + c0) = make_float4(v0, v1, v2, v3);
        } else {
          float4 o;
          o.x = fmaxf(v0, 0.f) + log1pf(__expf(-fabsf(v0))) + 1e-6f;
          o.y = fmaxf(v1, 0.f) + log1pf(__expf(-fabsf(v1))) + 1e-6f;
          o.z = fmaxf(v2, 0.f) + log1pf(__expf(-fabsf(v2))) + 1e-6f;
          o.w = fmaxf(v3, 0.f) + log1pf(__expf(-fabsf(v3))) + 1e-6f;
          *(float4*)(Y2 + m * 32 + (c0 - 32)) = o;
        }
      }
    } else if (ok && Y) {
      *(float4*)(Y + m * 64 + c0) = make_float4(v0, v1, v2, v3);
    }
    if (a_s) {
      float s = acc[r][0] * asv.x + acc[r][1] * asv.y + acc[r][2] * asv.z + acc[r][3] * asv.w;
      s += __shfl_xor(s, 1); s += __shfl_xor(s, 2);
      s += __shfl_xor(s, 4); s += __shfl_xor(s, 8);
      if (ok && cg == 0) al_s[m] = s;
    }
    if (a_d) {
      float s = acc[r][0] * adv.x + acc[r][1] * adv.y + acc[r][2] * adv.z + acc[r][3] * adv.w;
      s += __shfl_xor(s, 1); s += __shfl_xor(s, 2);
      s += __shfl_xor(s, 4); s += __shfl_xor(s, 8);
      if (ok && cg == 0) al_d[m] = s;
    }
  }
}

// ---------------------------------------------------------------------------
// NOUT=256 projection (tiled, BR=32): X and W staged in LDS.
// mode: 3 = store bf16 (used for all H=4 hs tables)
// ---------------------------------------------------------------------------
__global__ __launch_bounds__(256) void proj_kernel(
    XSrc xsrc, int M, int K,
    const float* __restrict__ W, const float* __restrict__ bias, int mode,
    const float* __restrict__ a_s, const float* __restrict__ a_d,
    float* __restrict__ al_s, float* __restrict__ al_d,
    float* __restrict__ Y, float* __restrict__ Y2) {
  constexpr int NOUT = 256;
  constexpr int KC = 32;
  constexpr int RPT = 8;
  constexpr int BR = 32;
  constexpr int KCP = 36;
  constexpr int H = 4;
  __shared__ float wl[KC * NOUT];
  __shared__ float xl[BR * KCP];

  int t = threadIdx.x;
  int cg = t & 63, rg = t >> 6;
  int c0 = cg * 4;
  long row0 = (long)blockIdx.x * BR;

  float acc[RPT][4];
#pragma unroll
  for (int r = 0; r < RPT; ++r)
#pragma unroll
    for (int j = 0; j < 4; ++j) acc[r][j] = 0.f;

  for (int k0 = 0; k0 < K; k0 += KC) {
    int kc = min(KC, K - k0);
    int seg = 0; int base = 0;
    while (k0 >= base + xsrc.w[seg]) { base += xsrc.w[seg]; ++seg; }
    const float* Xp = xsrc.p[seg];
    int stride = xsrc.w[seg];
    int kloc = k0 - base;

    __syncthreads();
    {
      const float4* wsrc = (const float4*)(W + (long)k0 * NOUT);
      float4* wdst = (float4*)wl;
      for (int i = t; i < (kc * NOUT) >> 2; i += 256) wdst[i] = wsrc[i];
    }
    for (int i = t; i < BR * 8; i += 256) {
      int r = i >> 3, kq = (i & 7) * 4;
      if (kq < kc) {
        long rr = row0 + r; if (rr >= M) rr = M - 1;
        float4 v = *(const float4*)(Xp + rr * stride + kloc + kq);
        *(float4*)(xl + r * KCP + kq) = v;
      }
    }
    __syncthreads();

    for (int kg = 0; kg < kc; kg += 4) {
      float4 w0 = *(const float4*)(wl + (kg + 0) * NOUT + c0);
      float4 w1 = *(const float4*)(wl + (kg + 1) * NOUT + c0);
      float4 w2 = *(const float4*)(wl + (kg + 2) * NOUT + c0);
      float4 w3 = *(const float4*)(wl + (kg + 3) * NOUT + c0);
      float4 xv[RPT];
#pragma unroll
      for (int r = 0; r < RPT; ++r)
        xv[r] = *(const float4*)(xl + (rg * RPT + r) * KCP + kg);
#pragma unroll
      for (int r = 0; r < RPT; ++r) {
        acc[r][0] = fmaf(xv[r].x, w0.x, acc[r][0]);
        acc[r][1] = fmaf(xv[r].x, w0.y, acc[r][1]);
        acc[r][2] = fmaf(xv[r].x, w0.z, acc[r][2]);
        acc[r][3] = fmaf(xv[r].x, w0.w, acc[r][3]);
        acc[r][0] = fmaf(xv[r].y, w1.x, acc[r][0]);
        acc[r][1] = fmaf(xv[r].y, w1.y, acc[r][1]);
        acc[r][2] = fmaf(xv[r].y, w1.z, acc[r][2]);
        acc[r][3] = fmaf(xv[r].y, w1.w, acc[r][3]);
        acc[r][0] = fmaf(xv[r].z, w2.x, acc[r][0]);
        acc[r][1] = fmaf(xv[r].z, w2.y, acc[r][1]);
        acc[r][2] = fmaf(xv[r].z, w2.z, acc[r][2]);
        acc[r][3] = fmaf(xv[r].z, w2.w, acc[r][3]);
        acc[r][0] = fmaf(xv[r].w, w3.x, acc[r][0]);
        acc[r][1] = fmaf(xv[r].w, w3.y, acc[r][1]);
        acc[r][2] = fmaf(xv[r].w, w3.z, acc[r][2]);
        acc[r][3] = fmaf(xv[r].w, w3.w, acc[r][3]);
      }
    }
  }

  float4 asv = make_float4(0.f, 0.f, 0.f, 0.f);
  float4 adv = make_float4(0.f, 0.f, 0.f, 0.f);
  if (a_s) asv = *(const float4*)(a_s + c0);
  if (a_d) adv = *(const float4*)(a_d + c0);

#pragma unroll
  for (int r = 0; r < RPT; ++r) {
    long m = row0 + (long)rg * RPT + r;
    bool ok = m < M;
    if (ok && mode == 3) {
      ushort4 o;
      o.x = f2bf(acc[r][0]); o.y = f2bf(acc[r][1]);
      o.z = f2bf(acc[r][2]); o.w = f2bf(acc[r][3]);
      *(ushort4*)((unsigned short*)Y + m * NOUT + c0) = o;
    }
    if (a_s) {
      float s = acc[r][0] * asv.x + acc[r][1] * asv.y + acc[r][2] * asv.z + acc[r][3] * asv.w;
      s += __shfl_xor(s, 1); s += __shfl_xor(s, 2);
      s += __shfl_xor(s, 4); s += __shfl_xor(s, 8);
      if (ok && (cg & 15) == 0) al_s[m * H + (c0 >> 6)] = s;
    }
    if (a_d) {
      float s = acc[r][0] * adv.x + acc[r][1] * adv.y + acc[r][2] * adv.z + acc[r][3] * adv.w;
      s += __shfl_xor(s, 1); s += __shfl_xor(s, 2);
      s += __shfl_xor(s, 4); s += __shfl_xor(s, 8);
      if (ok && (cg & 15) == 0) al_d[m * H + (c0 >> 6)] = s;
    }
  }
  (void)bias; (void)Y2;
}

// ---------------------------------------------------------------------------
// GAT pass A: thread = (node, head), h fastest.  Sweep 1: gather al_s, store
// logit l into alpha[] (and track max).  Sweep 2: re-read alpha sequentially
// (L2-hot) for exp/den — no second random gather.
// ---------------------------------------------------------------------------
template <int H, bool SELFLOOP>
__global__ void attn_kernel(
    int Nd, const int* __restrict__ dptr, const int* __restrict__ csr_src,
    const float* __restrict__ csr_ea, const float* __restrict__ al_s,
    const float* __restrict__ al_d, const float* __restrict__ dote,
    const float* __restrict__ loop_ea,
    float* __restrict__ alpha, float* __restrict__ aloop, float* __restrict__ invden) {
  int tid = blockIdx.x * blockDim.x + threadIdx.x;
  if (tid >= Nd * H) return;
  int n = tid / H, h = tid % H;
  float ald = al_d[(long)n * H + h];
  float de = dote[h];
  int e0 = dptr[n], e1 = dptr[n + 1];
  float m = -INFINITY;
  for (int e = e0; e < e1; ++e) {
    int src = csr_src[e];
    float l = al_s[(long)src * H + h] + ald + csr_ea[e] * de;
    l = (l > 0.f) ? l : 0.2f * l;
    alpha[(long)e * H + h] = l;
    m = fmaxf(m, l);
  }
  float lloop = 0.f;
  if (SELFLOOP) {
    lloop = al_s[(long)n * H + h] + ald + loop_ea[n] * de;
    lloop = (lloop > 0.f) ? lloop : 0.2f * lloop;
    m = fmaxf(m, lloop);
  }
  float den = 0.f;
  for (int e = e0; e < e1; ++e) {
    float ex = __expf(alpha[(long)e * H + h] - m);
    den += ex;
    alpha[(long)e * H + h] = ex;
  }
  if (SELFLOOP) {
    float ex = __expf(lloop - m);
    den += ex;
    aloop[(long)n * H + h] = ex;
  }
  invden[(long)n * H + h] = 1.f / (den + 1e-16f);
}

// ---------------------------------------------------------------------------
// GAT pass B, H=4 C=64 over bf16 hs (512B rows): one wave per node.
// ---------------------------------------------------------------------------
__device__ __forceinline__ void fma4_bf(float4& a, float al, ushort4 u) {
  a.x = fmaf(al, bf2f(u.x), a.x); a.y = fmaf(al, bf2f(u.y), a.y);
  a.z = fmaf(al, bf2f(u.z), a.z); a.w = fmaf(al, bf2f(u.w), a.w);
}

template <bool SELFLOOP>
__global__ __launch_bounds__(256) void agg4_kernel(
    int Nd, const int* __restrict__ dptr, const int* __restrict__ csr_src,
    const float* __restrict__ alpha, const float* __restrict__ aloop,
    const float* __restrict__ invden, const unsigned short* __restrict__ hs,
    const float* __restrict__ bias, float* __restrict__ out) {
  int wave = threadIdx.x >> 6, lane = threadIdx.x & 63;
  int n = blockIdx.x * 4 + wave;
  if (n >= Nd) return;
  int h = lane >> 4;
  int e0 = dptr[n], e1 = dptr[n + 1];
  float4 a0v = make_float4(0.f, 0.f, 0.f, 0.f);
  float4 a1v = make_float4(0.f, 0.f, 0.f, 0.f);
  int e = e0;
  for (; e + 2 <= e1; e += 2) {
    int s0 = csr_src[e], s1 = csr_src[e + 1];
    float a0 = alpha[(long)e * 4 + h];
    float a1 = alpha[(long)(e + 1) * 4 + h];
    ushort4 u0 = *(const ushort4*)(hs + (long)s0 * 256 + lane * 4);
    ushort4 u1 = *(const ushort4*)(hs + (long)s1 * 256 + lane * 4);
    fma4_bf(a0v, a0, u0);
    fma4_bf(a1v, a1, u1);
  }
  if (e < e1) {
    int s0 = csr_src[e];
    float a0 = alpha[(long)e * 4 + h];
    ushort4 u0 = *(const ushort4*)(hs + (long)s0 * 256 + lane * 4);
    fma4_bf(a0v, a0, u0);
  }
  a0v.x += a1v.x; a0v.y += a1v.y; a0v.z += a1v.z; a0v.w += a1v.w;
  if (SELFLOOP) {
    float a = aloop[(long)n * 4 + h];
    ushort4 u = *(const ushort4*)(hs + (long)n * 256 + lane * 4);
    fma4_bf(a0v, a, u);
  }
  float inv = invden[(long)n * 4 + h];
  a0v.x *= inv; a0v.y *= inv; a0v.z *= inv; a0v.w *= inv;
  a0v.x += __shfl_xor(a0v.x, 16); a0v.y += __shfl_xor(a0v.y, 16);
  a0v.z += __shfl_xor(a0v.z, 16); a0v.w += __shfl_xor(a0v.w, 16);
  a0v.x += __shfl_xor(a0v.x, 32); a0v.y += __shfl_xor(a0v.y, 32);
  a0v.z += __shfl_xor(a0v.z, 32); a0v.w += __shfl_xor(a0v.w, 32);
  if (lane < 16) {
    float4 b = *(const float4*)(bias + lane * 4);
    float4 o;
    o.x = fmaxf(a0v.x * 0.25f + b.x, 0.f);
    o.y = fmaxf(a0v.y * 0.25f + b.y, 0.f);
    o.z = fmaxf(a0v.z * 0.25f + b.z, 0.f);
    o.w = fmaxf(a0v.w * 0.25f + b.w, 0.f);
    *(float4*)(out + (long)n * 64 + lane * 4) = o;
  }
}

// GAT pass B, H=1 C=64 (fp32 hs): wave per node, lane = channel.
__global__ __launch_bounds__(256) void agg1_kernel(
    int Nd, const int* __restrict__ dptr, const int* __restrict__ csr_src,
    const float* __restrict__ alpha, const float* __restrict__ invden,
    const float* __restrict__ hs, const float* __restrict__ bias,
    float* __restrict__ out) {
  int wave = threadIdx.x >> 6, lane = threadIdx.x & 63;
  int n = blockIdx.x * 4 + wave;
  if (n >= Nd) return;
  int e0 = dptr[n], e1 = dptr[n + 1];
  float acc0 = 0.f, acc1 = 0.f;
  int e = e0;
  for (; e + 2 <= e1; e += 2) {
    int s0 = csr_src[e], s1 = csr_src[e + 1];
    acc0 = fmaf(alpha[e], hs[(long)s0 * 64 + lane], acc0);
    acc1 = fmaf(alpha[e + 1], hs[(long)s1 * 64 + lane], acc1);
  }
  if (e < e1) acc0 = fmaf(alpha[e], hs[(long)csr_src[e] * 64 + lane], acc0);
  acc0 += acc1;
  float o = acc0 * invden[n];
  out[(long)n * 64 + lane] = fmaxf(o + bias[lane], 0.f);
}

// ---------------------------------------------------------------------------
extern "C" void kernel_launch(void* const* d_in, const int* in_sizes, int n_in,
                              void* d_out, int out_size, void* d_ws, size_t ws_size,
                              hipStream_t stream) {
  const float* sp_mean = (const float*)d_in[0];
  const float* sp_std  = (const float*)d_in[1];
  const void*  nanmask = d_in[2];
  const float* sp_gen  = (const float*)d_in[3];
  const float* sp_phy  = (const float*)d_in[4];
  const float* spat_x  = (const float*)d_in[5];
  const float* spat_g  = (const float*)d_in[6];
  const int*   ss_ei   = (const int*)d_in[7];
  const float* ss_ea   = (const float*)d_in[8];
  const int*   bip_ei  = (const int*)d_in[9];
  const float* bip_ea  = (const float*)d_in[10];
  const int*   sp_ei   = (const int*)d_in[11];
  const float* sp_ea   = (const float*)d_in[12];
  const float* sg0_W = (const float*)d_in[13]; const float* sg0_as = (const float*)d_in[14];
  const float* sg0_ad = (const float*)d_in[15]; const float* sg0_ae = (const float*)d_in[16];
  const float* sg0_We = (const float*)d_in[17]; const float* sg0_b = (const float*)d_in[18];
  const float* sg1_W = (const float*)d_in[19]; const float* sg1_as = (const float*)d_in[20];
  const float* sg1_ad = (const float*)d_in[21]; const float* sg1_ae = (const float*)d_in[22];
  const float* sg1_We = (const float*)d_in[23]; const float* sg1_b = (const float*)d_in[24];
  const float* pg0_W = (const float*)d_in[25]; const float* pg0_as = (const float*)d_in[26];
  const float* pg0_ad = (const float*)d_in[27]; const float* pg0_ae = (const float*)d_in[28];
  const float* pg0_We = (const float*)d_in[29]; const float* pg0_b = (const float*)d_in[30];
  const float* pg1_W = (const float*)d_in[31]; const float* pg1_as = (const float*)d_in[32];
  const float* pg1_ad = (const float*)d_in[33]; const float* pg1_ae = (const float*)d_in[34];
  const float* pg1_We = (const float*)d_in[35]; const float* pg1_b = (const float*)d_in[36];
  const float* bp_Ws = (const float*)d_in[37]; const float* bp_Wd = (const float*)d_in[38];
  const float* bp_as = (const float*)d_in[39]; const float* bp_ad = (const float*)d_in[40];
  const float* bp_ae = (const float*)d_in[41]; const float* bp_We = (const float*)d_in[42];
  const float* bp_b  = (const float*)d_in[43];
  const float* sl_W  = (const float*)d_in[44]; const float* sl_b  = (const float*)d_in[45];
  const float* fc_W  = (const float*)d_in[46]; const float* fc_b  = (const float*)d_in[47];

  // ---- workspace layout ----
  char* wsb = (char*)d_ws;
  size_t off = 0;
  auto A = [&](size_t nbytes) -> void* {
    void* p = wsb + off;
    off += (nbytes + 255) & ~(size_t)255;
    return p;
  };
  // --- zeroed region (single memset): partitioned counters ---
  int* ss_cp = (int*)A((size_t)8 * NSPAT * 4);
  int* bp_cp = (int*)A((size_t)8 * NSP * 4);
  int* pp_cp = (int*)A((size_t)8 * NSP * 4);
  size_t zbytes = off;
  // --- rest ---
  int*   ss_cnt = (int*)A((NSPAT + 1) * 4);
  int*   bp_cnt = (int*)A((NSP + 1) * 4);
  int*   pp_cnt = (int*)A((NSP + 1) * 4);
  int*   flag  = (int*)A(4);
  float* dotes = (float*)A(5 * 4 * sizeof(float));
  float* alS   = (float*)A((size_t)NSP * 4 * 4);
  float* alD   = (float*)A((size_t)NSP * 4 * 4);
  float* spc96 = (float*)A((size_t)NSP * 96 * 4);
  float* sp_in = (float*)A((size_t)NSP * 64 * 4);
  float* h0    = (float*)A((size_t)NSPAT * 16 * 4);
  float* h_a   = (float*)A((size_t)NSPAT * 64 * 4);
  float* h_b   = (float*)A((size_t)NSPAT * 64 * 4);
  float* HS    = (float*)A((size_t)NSP * 256 * 4);   // bf16 hs rows
  float* sts   = (float*)A((size_t)NSP * 64 * 4);
  float* x1    = (float*)A((size_t)NSP * 64 * 4);
  int*   ss_ptr = (int*)A((NSPAT + 1) * 4);
  int*   ss_src = (int*)A((size_t)ESS * 4);
  float* ss_cea = (float*)A((size_t)ESS * 4);
  int*   ss_rnk = (int*)A((size_t)ESS * 4);
  float* ss_lea = (float*)A((size_t)NSPAT * 4);
  int*   bp_ptr = (int*)A((NSP + 1) * 4);
  int*   bp_src = (int*)A((size_t)EBIP * 4);
  float* bp_cea = (float*)A((size_t)EBIP * 4);
  int*   bp_rnk = (int*)A((size_t)EBIP * 4);
  int*   pp_ptr = (int*)A((NSP + 1) * 4);
  int*   pp_src = (int*)A((size_t)ESP * 4);
  float* pp_cea = (float*)A((size_t)ESP * 4);
  int*   pp_rnk = (int*)A((size_t)ESP * 4);
  float* pp_lea = (float*)A((size_t)NSP * 4);
  float* ss_alpha = (float*)A((size_t)ESS * 4 * 4);
  float* ss_aloop = (float*)A((size_t)NSPAT * 4 * 4);
  float* ss_invd  = (float*)A((size_t)NSPAT * 4 * 4);
  float* bp_alpha = (float*)A((size_t)EBIP * 4);
  float* bp_invd  = (float*)A((size_t)NSP * 4);
  float* pp_alpha = (float*)A((size_t)ESP * 4 * 4);
  float* pp_aloop = (float*)A((size_t)NSP * 4 * 4);
  float* pp_invd  = (float*)A((size_t)NSP * 4 * 4);
  (void)ws_size; (void)in_sizes; (void)n_in; (void)out_size;

  const int TB = 256;
  hipMemsetAsync(wsb, 0, zbytes, stream);

  // ---- graph builds: partitioned count -> merge -> scan -> scatter ----
  count3_kernel<<<cdiv_host(ESS + EBIP + ESP, TB), TB, 0, stream>>>(
      ss_ei + ESS, ESS, ss_cp, ss_rnk, NSPAT,
      bip_ei + EBIP, EBIP, bp_cp, bp_rnk, NSP,
      sp_ei + ESP, ESP, pp_cp, pp_rnk, NSP);
  merge3_kernel<<<cdiv_host(NSPAT + NSP + NSP, TB), TB, 0, stream>>>(
      ss_cp, ss_cnt, NSPAT, bp_cp, bp_cnt, NSP, pp_cp, pp_cnt, NSP);
  scan3_kernel<<<3, 1024, 0, stream>>>(ss_cnt, NSPAT, ss_ptr, bp_cnt, NSP, bp_ptr, pp_cnt, NSP, pp_ptr);
  scatter3_kernel<<<cdiv_host(ESS + EBIP + ESP, TB), TB, 0, stream>>>(
      ss_ei, ss_ei + ESS, ss_ea, ESS, ss_ptr, ss_cp, ss_rnk, NSPAT, ss_src, ss_cea,
      bip_ei, bip_ei + EBIP, bip_ea, EBIP, bp_ptr, bp_cp, bp_rnk, NSP, bp_src, bp_cea,
      sp_ei, sp_ei + ESP, sp_ea, ESP, pp_ptr, pp_cp, pp_rnk, NSP, pp_src, pp_cea);
  leafin_csr2<<<cdiv_host(NSPAT + NSP, TB), TB, 0, stream>>>(
      ss_ptr, ss_cea, NSPAT, ss_lea, pp_ptr, pp_cea, NSP, pp_lea);

  dote_all_kernel<<<6, 256, 0, stream>>>(sg0_We, sg0_ae, sg1_We, sg1_ae, bp_We, bp_ae,
                                         pg0_We, pg0_ae, pg1_We, pg1_ae,
                                         (const unsigned int*)nanmask, dotes, flag);

  // ---- prep: spc96 + h0 in one launch ----
  build_pre_kernel<<<cdiv_host((long)NSP * 96 + (long)NSPAT * 16, TB), TB, 0, stream>>>(
      sp_mean, sp_std, nanmask, flag, spat_x, spat_g, spc96, h0);

  // ---- species input MLP ----
  {
    XSrc xs{}; xs.p[0] = spc96; xs.w[0] = 96; xs.p[1] = sp_gen; xs.w[1] = 64;
    xs.p[2] = sp_phy; xs.w[2] = 128; xs.n = 3;
    proj64_kernel<<<cdiv_host(NSP, 32), TB, 0, stream>>>(xs, NSP, 288, sl_W, sl_b, 1,
        nullptr, nullptr, nullptr, nullptr, sp_in, nullptr);
  }

  // ---- spatial GNN ----
  {
    XSrc xs{}; xs.p[0] = h0; xs.w[0] = 16; xs.n = 1;
    proj_kernel<<<cdiv_host(NSPAT, 32), TB, 0, stream>>>(xs, NSPAT, 16, sg0_W, nullptr, 3,
        sg0_as, sg0_ad, alS, alD, HS, nullptr);
  }
  attn_kernel<4, true><<<cdiv_host((long)NSPAT * 4, TB), TB, 0, stream>>>(
      NSPAT, ss_ptr, ss_src, ss_cea, alS, alD, dotes + 0, ss_lea, ss_alpha, ss_aloop, ss_invd);
  agg4_kernel<true><<<cdiv_host(NSPAT, 4), TB, 0, stream>>>(
      NSPAT, ss_ptr, ss_src, ss_alpha, ss_aloop, ss_invd, (const unsigned short*)HS, sg0_b, h_a);
  {
    XSrc xs{}; xs.p[0] = h_a; xs.w[0] = 64; xs.n = 1;
    proj_kernel<<<cdiv_host(NSPAT, 32), TB, 0, stream>>>(xs, NSPAT, 64, sg1_W, nullptr, 3,
        sg1_as, sg1_ad, alS, alD, HS, nullptr);
  }
  attn_kernel<4, true><<<cdiv_host((long)NSPAT * 4, TB), TB, 0, stream>>>(
      NSPAT, ss_ptr, ss_src, ss_cea, alS, alD, dotes + 4, ss_lea, ss_alpha, ss_aloop, ss_invd);
  agg4_kernel<true><<<cdiv_host(NSPAT, 4), TB, 0, stream>>>(
      NSPAT, ss_ptr, ss_src, ss_alpha, ss_aloop, ss_invd, (const unsigned short*)HS, sg1_b, h_b);

  // ---- bipartite GAT (spatial -> species), H=1, concat ----
  {
    XSrc xs{}; xs.p[0] = h_b; xs.w[0] = 64; xs.n = 1;
    proj64_kernel<<<cdiv_host(NSPAT, 32), TB, 0, stream>>>(xs, NSPAT, 64, bp_Ws, nullptr, 0,
        bp_as, nullptr, alS, nullptr, h_a, nullptr);   // h_a := hs_src (fp32)
  }
  {
    XSrc xs{}; xs.p[0] = sp_gen; xs.w[0] = 64; xs.p[1] = sp_phy; xs.w[1] = 128; xs.n = 2;
    proj64_kernel<<<cdiv_host(NSP, 32), TB, 0, stream>>>(xs, NSP, 192, bp_Wd, nullptr, 0,
        nullptr, bp_ad, nullptr, alD, nullptr, nullptr);   // only al_d needed
  }
  attn_kernel<1, false><<<cdiv_host(NSP, TB), TB, 0, stream>>>(
      NSP, bp_ptr, bp_src, bp_cea, alS, alD, dotes + 8, nullptr, bp_alpha, nullptr, bp_invd);
  agg1_kernel<<<cdiv_host(NSP, 4), TB, 0, stream>>>(
      NSP, bp_ptr, bp_src, bp_alpha, bp_invd, h_a, bp_b, sts);

  // ---- species GNN ----
  {
    XSrc xs{}; xs.p[0] = sts; xs.w[0] = 64; xs.p[1] = sp_in; xs.w[1] = 64; xs.n = 2;
    proj_kernel<<<cdiv_host(NSP, 32), TB, 0, stream>>>(xs, NSP, 128, pg0_W, nullptr, 3,
        pg0_as, pg0_ad, alS, alD, HS, nullptr);
  }
  attn_kernel<4, true><<<cdiv_host((long)NSP * 4, TB), TB, 0, stream>>>(
      NSP, pp_ptr, pp_src, pp_cea, alS, alD, dotes + 12, pp_lea, pp_alpha, pp_aloop, pp_invd);
  agg4_kernel<true><<<cdiv_host(NSP, 4), TB, 0, stream>>>(
      NSP, pp_ptr, pp_src, pp_alpha, pp_aloop, pp_invd, (const unsigned short*)HS, pg0_b, x1);
  {
    XSrc xs{}; xs.p[0] = x1; xs.w[0] = 64; xs.n = 1;
    proj_kernel<<<cdiv_host(NSP, 32), TB, 0, stream>>>(xs, NSP, 64, pg1_W, nullptr, 3,
        pg1_as, pg1_ad, alS, alD, HS, nullptr);
  }
  attn_kernel<4, true><<<cdiv_host((long)NSP * 4, TB), TB, 0, stream>>>(
      NSP, pp_ptr, pp_src, pp_cea, alS, alD, dotes + 16, pp_lea, pp_alpha, pp_aloop, pp_invd);
  agg4_kernel<true><<<cdiv_host(NSP, 4), TB, 0, stream>>>(
      NSP, pp_ptr, pp_src, pp_alpha, pp_aloop, pp_invd, (const unsigned short*)HS, pg1_b, sts);

  // ---- final linear fused with split/softplus ----
  {
    XSrc xs{}; xs.p[0] = sts; xs.w[0] = 64; xs.n = 1;
    proj64_kernel<<<cdiv_host(NSP, 32), TB, 0, stream>>>(xs, NSP, 64, fc_W, fc_b, 2,
        nullptr, nullptr, nullptr, nullptr, (float*)d_out, (float*)d_out + (long)NSP * 32);
  }
}